// Round 1
// 1162.623 us; speedup vs baseline: 1.0150x; 1.0150x over previous
//
#include <hip/hip_runtime.h>

#define N_USERS 200000
#define N_ITEMS 100000
#define N_NODES 300000
#define EMB     64
#define N_EDGES 5000000

struct alignas(8) Edge  { int col; float val; };
struct Edge3 { int row; int col; float val; };   // 12 B staged record

// ---------------------------------------------------------------------------
// init: x = concat(emb_user, emb_item); out = x  (layer-sum seeded with x0)
// ---------------------------------------------------------------------------
__global__ __launch_bounds__(256) void init_kernel(
    const float* __restrict__ user, const float* __restrict__ item,
    float* __restrict__ x, float* __restrict__ out)
{
    const int nu4 = N_USERS * EMB / 4;
    const int nt4 = N_NODES * EMB / 4;
    int i = blockIdx.x * blockDim.x + threadIdx.x;
    if (i >= nt4) return;
    float4 v = (i < nu4) ? reinterpret_cast<const float4*>(user)[i]
                         : reinterpret_cast<const float4*>(item)[i - nu4];
    reinterpret_cast<float4*>(x)[i]   = v;
    reinterpret_cast<float4*>(out)[i] = v;
}

// ---------------------------------------------------------------------------
// CSR build step 1: per-row edge counts
// ---------------------------------------------------------------------------
__global__ __launch_bounds__(256) void count_kernel(
    const int* __restrict__ row, int* __restrict__ cnt)
{
    int e = blockIdx.x * blockDim.x + threadIdx.x;
    if (e < N_EDGES) atomicAdd(&cnt[row[e]], 1);
}

// ---------------------------------------------------------------------------
// CSR build step 2: hierarchical exclusive scan (3 phases, full-GPU parallel)
// ---------------------------------------------------------------------------
#define SCAN_BLOCKS ((N_NODES + 255) / 256)   // 1172

__global__ __launch_bounds__(256) void bsum_kernel(
    const int* __restrict__ cnt, int* __restrict__ bsum)
{
    __shared__ int s[256];
    int t = threadIdx.x;
    int i = blockIdx.x * 256 + t;
    s[t] = (i < N_NODES) ? cnt[i] : 0;
    __syncthreads();
    for (int ofs = 128; ofs > 0; ofs >>= 1) {
        if (t < ofs) s[t] += s[t + ofs];
        __syncthreads();
    }
    if (t == 0) bsum[blockIdx.x] = s[0];
}

__global__ __launch_bounds__(1024) void bscan_kernel(
    const int* __restrict__ bsum, int* __restrict__ bpre)
{
    __shared__ int s[1024];
    const int SEG = (SCAN_BLOCKS + 1023) / 1024;   // 2
    int t  = threadIdx.x;
    int lo = t * SEG;
    int hi = lo + SEG; if (hi > SCAN_BLOCKS) hi = SCAN_BLOCKS;
    int sum = 0;
    for (int i = lo; i < hi && i < SCAN_BLOCKS; ++i) sum += bsum[i];
    s[t] = sum;
    __syncthreads();
    for (int ofs = 1; ofs < 1024; ofs <<= 1) {
        int v = (t >= ofs) ? s[t - ofs] : 0;
        __syncthreads();
        s[t] += v;
        __syncthreads();
    }
    int running = s[t] - sum;
    for (int i = lo; i < hi && i < SCAN_BLOCKS; ++i) {
        bpre[i] = running;
        running += bsum[i];
    }
}

__global__ __launch_bounds__(256) void scan_apply_kernel(
    const int* __restrict__ cnt, const int* __restrict__ bpre,
    int* __restrict__ start)
{
    __shared__ int s[256];
    int t = threadIdx.x;
    int i = blockIdx.x * 256 + t;
    int v = (i < N_NODES) ? cnt[i] : 0;
    s[t] = v;
    __syncthreads();
    for (int ofs = 1; ofs < 256; ofs <<= 1) {
        int w = (t >= ofs) ? s[t - ofs] : 0;
        __syncthreads();
        s[t] += w;
        __syncthreads();
    }
    int excl = s[t] - v + bpre[blockIdx.x];
    if (i < N_NODES) start[i] = excl;
    if (blockIdx.x == 0 && t == 0) start[N_NODES] = N_EDGES;
}

// ---------------------------------------------------------------------------
// Two-phase bucketed scatter. Bucket = row >> 9 (512 rows, 586 buckets).
// BSHIFT 11->9: bucket_scatter grid 147->586 WGs (was using 57% of CUs).
// Single-writer-per-window property preserved (1 WG per bucket window).
// ---------------------------------------------------------------------------
#define BSHIFT 9
#define BROWS  (1 << BSHIFT)
#define NBUCK  ((N_NODES + BROWS - 1) >> BSHIFT)           // 586
#define BIN_EPT   16
#define BIN_BLK   256
#define BIN_CHUNK (BIN_BLK * BIN_EPT)                      // 4096 edges/block

__global__ __launch_bounds__(256) void binit_kernel(
    const int* __restrict__ start, int* __restrict__ bcursor)
{
    for (int k = threadIdx.x; k < NBUCK; k += blockDim.x) {
        int lo = k << BSHIFT;
        if (lo > N_NODES) lo = N_NODES;
        bcursor[k] = start[lo];
    }
}

// phase 1: bin edges into bucket-contiguous staging (dense, line-friendly)
__global__ __launch_bounds__(256) void bin_kernel(
    const int* __restrict__ row, const int* __restrict__ col,
    const float* __restrict__ val, int* __restrict__ bcursor,
    Edge3* __restrict__ stage)
{
    __shared__ int hist[NBUCK];
    __shared__ int base[NBUCK];
    int t = threadIdx.x;
    long e0 = (long)blockIdx.x * BIN_CHUNK;

    int   r[BIN_EPT]; int c[BIN_EPT]; float v[BIN_EPT];
    for (int k = t; k < NBUCK; k += 256) hist[k] = 0;
    __syncthreads();

    int n = 0;
    #pragma unroll
    for (int k = 0; k < BIN_EPT; ++k) {
        long e = e0 + (long)k * BIN_BLK + t;
        if (e < N_EDGES) {
            r[k] = row[e]; c[k] = col[e]; v[k] = val[e];
            atomicAdd(&hist[r[k] >> BSHIFT], 1);
            n = k + 1;
        }
    }
    __syncthreads();
    for (int k = t; k < NBUCK; k += 256) {
        int h = hist[k];
        base[k] = h ? atomicAdd(&bcursor[k], h) : 0;
        hist[k] = 0;    // reuse as local cursor
    }
    __syncthreads();
    #pragma unroll
    for (int k = 0; k < BIN_EPT; ++k) {
        if (k < n) {
            long e = e0 + (long)k * BIN_BLK + t;
            if (e < N_EDGES) {
                int b   = r[k] >> BSHIFT;
                int pos = base[b] + atomicAdd(&hist[b], 1);
                Edge3 ed; ed.row = r[k]; ed.col = c[k]; ed.val = v[k];
                stage[pos] = ed;
            }
        }
    }
}

// phase 2: one WG per bucket. LDS row-cursors seeded from start[]; the
// ~68 KB destination window is written by exactly ONE CU -> lines merge in
// that XCD's L2; writeback ~= payload (fixes the 8-XCD false-sharing blowup).
__global__ __launch_bounds__(1024) void bucket_scatter_kernel(
    const Edge3* __restrict__ stage, const int* __restrict__ start,
    Edge* __restrict__ packed)
{
    __shared__ int cur[BROWS];
    int b    = blockIdx.x;
    int row0 = b << BSHIFT;
    int rows = N_NODES - row0; if (rows > BROWS) rows = BROWS;
    int t = threadIdx.x;

    for (int i = t; i < rows; i += 1024) cur[i] = start[row0 + i];
    __syncthreads();

    int ebeg = start[row0];
    int eend = start[row0 + rows];
    for (int e = ebeg + t; e < eend; e += 1024) {
        Edge3 ed = stage[e];
        int pos = atomicAdd(&cur[ed.row - row0], 1);
        Edge p; p.col = ed.col; p.val = ed.val;
        packed[pos] = p;
    }
}

// ---------------------------------------------------------------------------
// CSR SpMM, fused with layer-sum update.
// 16 lanes per row, 4 dims per lane, register accumulation, no atomics.
// MLP restructure: batch-load 16 edges per row-group (lane l loads edge
// jb+l once, coalesced 128 B), broadcast (col,val) via __shfl within the
// 16-lane group, issue all 16 gathers from an unrolled loop -> 16+ gathers
// in flight per group instead of ~1 (addr no longer depends on an edge load
// inside the iteration).
// ---------------------------------------------------------------------------
__global__ __launch_bounds__(256) void spmm_csr_kernel(
    const float* __restrict__ x, const Edge* __restrict__ packed,
    const int* __restrict__ start,
    float* __restrict__ y, float* __restrict__ out, float scale)
{
    int g = blockIdx.x * (256 / 16) + (threadIdx.x >> 4);
    if (g >= N_NODES) return;
    const int lane16 = threadIdx.x & 15;
    const int d      = lane16 * 4;
    const int gbase  = threadIdx.x & 48;     // 16-group base lane within wave

    int beg = start[g];
    int end = start[g + 1];
    float4 acc = {0.f, 0.f, 0.f, 0.f};

    for (int jb = beg; jb < end; jb += 16) {
        int cnt = end - jb; if (cnt > 16) cnt = 16;
        Edge ed; ed.col = 0; ed.val = 0.f;
        if (lane16 < cnt) ed = packed[jb + lane16];
        #pragma unroll
        for (int k = 0; k < 16; ++k) {
            int   c = __shfl(ed.col, gbase + k, 64);
            float v = __shfl(ed.val, gbase + k, 64);
            if (k < cnt) {
                float4 xv = *reinterpret_cast<const float4*>(
                    x + (size_t)c * EMB + d);
                acc.x += v * xv.x;
                acc.y += v * xv.y;
                acc.z += v * xv.z;
                acc.w += v * xv.w;
            }
        }
    }

    *reinterpret_cast<float4*>(y + (size_t)g * EMB + d) = acc;

    float4 o = *reinterpret_cast<float4*>(out + (size_t)g * EMB + d);
    o.x = (o.x + acc.x) * scale;
    o.y = (o.y + acc.y) * scale;
    o.z = (o.z + acc.z) * scale;
    o.w = (o.w + acc.w) * scale;
    *reinterpret_cast<float4*>(out + (size_t)g * EMB + d) = o;
}

// ---------------------------------------------------------------------------
// Fallback path: edge-parallel atomics. Used only if ws too small for CSR.
// ---------------------------------------------------------------------------
__global__ __launch_bounds__(256) void spmm_atomic_kernel(
    const float* __restrict__ x, const float* __restrict__ val,
    const int* __restrict__ row, const int* __restrict__ col,
    float* __restrict__ y)
{
    int t = blockIdx.x * blockDim.x + threadIdx.x;
    int e = t >> 4;
    if (e >= N_EDGES) return;
    int d = (t & 15) * 4;
    int   r = row[e];
    int   c = col[e];
    float v = val[e];
    float4 xv = *reinterpret_cast<const float4*>(x + c * EMB + d);
    float* yp = y + r * EMB + d;
    unsafeAtomicAdd(yp + 0, v * xv.x);
    unsafeAtomicAdd(yp + 1, v * xv.y);
    unsafeAtomicAdd(yp + 2, v * xv.z);
    unsafeAtomicAdd(yp + 3, v * xv.w);
}

__global__ __launch_bounds__(256) void addscale_kernel(
    const float* __restrict__ xl, float* __restrict__ out, float scale)
{
    const int nt4 = N_NODES * EMB / 4;
    int i = blockIdx.x * blockDim.x + threadIdx.x;
    if (i >= nt4) return;
    float4 a = reinterpret_cast<float4*>(out)[i];
    float4 b = reinterpret_cast<const float4*>(xl)[i];
    a.x = (a.x + b.x) * scale;
    a.y = (a.y + b.y) * scale;
    a.z = (a.z + b.z) * scale;
    a.w = (a.w + b.w) * scale;
    reinterpret_cast<float4*>(out)[i] = a;
}

extern "C" void kernel_launch(void* const* d_in, const int* in_sizes, int n_in,
                              void* d_out, int out_size, void* d_ws, size_t ws_size,
                              hipStream_t stream) {
    const float* emb_user = (const float*)d_in[0];
    const float* emb_item = (const float*)d_in[1];
    const float* edge_val = (const float*)d_in[2];
    const int*   edge_row = (const int*)d_in[3];
    const int*   edge_col = (const int*)d_in[4];
    float* out = (float*)d_out;

    const size_t node_elems = (size_t)N_NODES * EMB;        // 19.2M floats
    char* ws = (char*)d_ws;

    // workspace layout (stage aliases bufB: dead until SpMM layer 0)
    const size_t off_bufA    = 0;
    const size_t off_bufB    = off_bufA + node_elems * sizeof(float);      // 76.8 MB
    const size_t off_packed  = off_bufB + node_elems * sizeof(float);      // 153.6 MB
    const size_t off_start   = off_packed + (size_t)N_EDGES * sizeof(Edge);// 193.6 MB
    const size_t off_cnt     = off_start + (N_NODES + 4) * sizeof(int);
    const size_t off_bsum    = off_cnt + N_NODES * sizeof(int);
    const size_t off_bpre    = off_bsum + SCAN_BLOCKS * sizeof(int);
    const size_t off_bcursor = off_bpre + SCAN_BLOCKS * sizeof(int);
    const size_t needed      = off_bcursor + (NBUCK + 4) * sizeof(int);    // ~196 MB

    float* bufA = (float*)(ws + off_bufA);
    float* bufB = (float*)(ws + off_bufB);

    const int nt4       = N_NODES * EMB / 4;
    const int el_blocks = (nt4 + 255) / 256;
    const int e_blocks  = (N_EDGES + 255) / 256;

    init_kernel<<<el_blocks, 256, 0, stream>>>(emb_user, emb_item, bufA, out);

    if (ws_size >= needed) {
        // ---- CSR path ----
        Edge*  packed  = (Edge*) (ws + off_packed);
        int*   start   = (int*)  (ws + off_start);
        int*   cnt     = (int*)  (ws + off_cnt);
        int*   bsum    = (int*)  (ws + off_bsum);
        int*   bpre    = (int*)  (ws + off_bpre);
        int*   bcursor = (int*)  (ws + off_bcursor);
        Edge3* stage   = (Edge3*)(ws + off_bufB);   // 60 MB inside bufB

        hipMemsetAsync(cnt, 0, N_NODES * sizeof(int), stream);
        count_kernel<<<e_blocks, 256, 0, stream>>>(edge_row, cnt);
        bsum_kernel<<<SCAN_BLOCKS, 256, 0, stream>>>(cnt, bsum);
        bscan_kernel<<<1, 1024, 0, stream>>>(bsum, bpre);
        scan_apply_kernel<<<SCAN_BLOCKS, 256, 0, stream>>>(cnt, bpre, start);
        binit_kernel<<<1, 256, 0, stream>>>(start, bcursor);
        const int bin_blocks = (N_EDGES + BIN_CHUNK - 1) / BIN_CHUNK;      // 1221
        bin_kernel<<<bin_blocks, 256, 0, stream>>>(edge_row, edge_col, edge_val,
                                                   bcursor, stage);
        bucket_scatter_kernel<<<NBUCK, 1024, 0, stream>>>(stage, start, packed);

        const int row_blocks = (N_NODES + 15) / 16;          // 16 rows / block
        float* cur = bufA;
        float* nxt = bufB;
        for (int layer = 0; layer < 3; ++layer) {
            spmm_csr_kernel<<<row_blocks, 256, 0, stream>>>(
                cur, packed, start, nxt, out,
                (layer == 2) ? 0.25f : 1.0f);
            float* tmp = cur; cur = nxt; nxt = tmp;
        }
    } else {
        // ---- fallback: atomic path (needs only 153.6 MB) ----
        const int ew_blocks = (N_EDGES * 16 + 255) / 256;
        float* cur = bufA;
        float* nxt = bufB;
        for (int layer = 0; layer < 3; ++layer) {
            hipMemsetAsync(nxt, 0, node_elems * sizeof(float), stream);
            spmm_atomic_kernel<<<ew_blocks, 256, 0, stream>>>(
                cur, edge_val, edge_row, edge_col, nxt);
            addscale_kernel<<<el_blocks, 256, 0, stream>>>(
                nxt, out, (layer == 2) ? 0.25f : 1.0f);
            float* tmp = cur; cur = nxt; nxt = tmp;
        }
    }
}

// Round 2
// 1151.443 us; speedup vs baseline: 1.0248x; 1.0097x over previous
//
#include <hip/hip_runtime.h>

#define N_USERS 200000
#define N_ITEMS 100000
#define N_NODES 300000
#define EMB     64
#define N_EDGES 5000000

struct alignas(8) Edge  { int col; float val; };
struct Edge3 { int row; int col; float val; };   // 12 B staged record

// ---------------------------------------------------------------------------
// init: x = concat(emb_user, emb_item); out = x  (layer-sum seeded with x0)
// ---------------------------------------------------------------------------
__global__ __launch_bounds__(256) void init_kernel(
    const float* __restrict__ user, const float* __restrict__ item,
    float* __restrict__ x, float* __restrict__ out)
{
    const int nu4 = N_USERS * EMB / 4;
    const int nt4 = N_NODES * EMB / 4;
    int i = blockIdx.x * blockDim.x + threadIdx.x;
    if (i >= nt4) return;
    float4 v = (i < nu4) ? reinterpret_cast<const float4*>(user)[i]
                         : reinterpret_cast<const float4*>(item)[i - nu4];
    reinterpret_cast<float4*>(x)[i]   = v;
    reinterpret_cast<float4*>(out)[i] = v;
}

// ---------------------------------------------------------------------------
// CSR build step 1: per-row edge counts
// ---------------------------------------------------------------------------
__global__ __launch_bounds__(256) void count_kernel(
    const int* __restrict__ row, int* __restrict__ cnt)
{
    int e = blockIdx.x * blockDim.x + threadIdx.x;
    if (e < N_EDGES) atomicAdd(&cnt[row[e]], 1);
}

// ---------------------------------------------------------------------------
// CSR build step 2: hierarchical exclusive scan (3 phases, full-GPU parallel)
// ---------------------------------------------------------------------------
#define SCAN_BLOCKS ((N_NODES + 255) / 256)   // 1172

__global__ __launch_bounds__(256) void bsum_kernel(
    const int* __restrict__ cnt, int* __restrict__ bsum)
{
    __shared__ int s[256];
    int t = threadIdx.x;
    int i = blockIdx.x * 256 + t;
    s[t] = (i < N_NODES) ? cnt[i] : 0;
    __syncthreads();
    for (int ofs = 128; ofs > 0; ofs >>= 1) {
        if (t < ofs) s[t] += s[t + ofs];
        __syncthreads();
    }
    if (t == 0) bsum[blockIdx.x] = s[0];
}

__global__ __launch_bounds__(1024) void bscan_kernel(
    const int* __restrict__ bsum, int* __restrict__ bpre)
{
    __shared__ int s[1024];
    const int SEG = (SCAN_BLOCKS + 1023) / 1024;   // 2
    int t  = threadIdx.x;
    int lo = t * SEG;
    int hi = lo + SEG; if (hi > SCAN_BLOCKS) hi = SCAN_BLOCKS;
    int sum = 0;
    for (int i = lo; i < hi && i < SCAN_BLOCKS; ++i) sum += bsum[i];
    s[t] = sum;
    __syncthreads();
    for (int ofs = 1; ofs < 1024; ofs <<= 1) {
        int v = (t >= ofs) ? s[t - ofs] : 0;
        __syncthreads();
        s[t] += v;
        __syncthreads();
    }
    int running = s[t] - sum;
    for (int i = lo; i < hi && i < SCAN_BLOCKS; ++i) {
        bpre[i] = running;
        running += bsum[i];
    }
}

__global__ __launch_bounds__(256) void scan_apply_kernel(
    const int* __restrict__ cnt, const int* __restrict__ bpre,
    int* __restrict__ start)
{
    __shared__ int s[256];
    int t = threadIdx.x;
    int i = blockIdx.x * 256 + t;
    int v = (i < N_NODES) ? cnt[i] : 0;
    s[t] = v;
    __syncthreads();
    for (int ofs = 1; ofs < 256; ofs <<= 1) {
        int w = (t >= ofs) ? s[t - ofs] : 0;
        __syncthreads();
        s[t] += w;
        __syncthreads();
    }
    int excl = s[t] - v + bpre[blockIdx.x];
    if (i < N_NODES) start[i] = excl;
    if (blockIdx.x == 0 && t == 0) start[N_NODES] = N_EDGES;
}

// ---------------------------------------------------------------------------
// Two-phase bucketed scatter. Bucket = row >> 11 (2048 rows, 147 buckets).
// (BSHIFT 9 experiment in R1 regressed the build phase ~35 us; reverted.)
// ---------------------------------------------------------------------------
#define BSHIFT 11
#define BROWS  (1 << BSHIFT)
#define NBUCK  ((N_NODES + BROWS - 1) >> BSHIFT)           // 147
#define BIN_EPT   16
#define BIN_BLK   256
#define BIN_CHUNK (BIN_BLK * BIN_EPT)                      // 4096 edges/block

__global__ __launch_bounds__(256) void binit_kernel(
    const int* __restrict__ start, int* __restrict__ bcursor)
{
    for (int k = threadIdx.x; k < NBUCK; k += blockDim.x) {
        int lo = k << BSHIFT;
        if (lo > N_NODES) lo = N_NODES;
        bcursor[k] = start[lo];
    }
}

// phase 1: bin edges into bucket-contiguous staging (dense, line-friendly)
__global__ __launch_bounds__(256) void bin_kernel(
    const int* __restrict__ row, const int* __restrict__ col,
    const float* __restrict__ val, int* __restrict__ bcursor,
    Edge3* __restrict__ stage)
{
    __shared__ int hist[NBUCK];
    __shared__ int base[NBUCK];
    int t = threadIdx.x;
    long e0 = (long)blockIdx.x * BIN_CHUNK;

    int   r[BIN_EPT]; int c[BIN_EPT]; float v[BIN_EPT];
    for (int k = t; k < NBUCK; k += 256) hist[k] = 0;
    __syncthreads();

    int n = 0;
    #pragma unroll
    for (int k = 0; k < BIN_EPT; ++k) {
        long e = e0 + (long)k * BIN_BLK + t;
        if (e < N_EDGES) {
            r[k] = row[e]; c[k] = col[e]; v[k] = val[e];
            atomicAdd(&hist[r[k] >> BSHIFT], 1);
            n = k + 1;
        }
    }
    __syncthreads();
    for (int k = t; k < NBUCK; k += 256) {
        int h = hist[k];
        base[k] = h ? atomicAdd(&bcursor[k], h) : 0;
        hist[k] = 0;    // reuse as local cursor
    }
    __syncthreads();
    #pragma unroll
    for (int k = 0; k < BIN_EPT; ++k) {
        if (k < n) {
            long e = e0 + (long)k * BIN_BLK + t;
            if (e < N_EDGES) {
                int b   = r[k] >> BSHIFT;
                int pos = base[b] + atomicAdd(&hist[b], 1);
                Edge3 ed; ed.row = r[k]; ed.col = c[k]; ed.val = v[k];
                stage[pos] = ed;
            }
        }
    }
}

// phase 2: one WG per bucket. LDS row-cursors seeded from start[]; the
// ~273 KB destination window is written by exactly ONE CU -> lines merge in
// that XCD's L2; writeback ~= payload (fixes the 8-XCD false-sharing blowup).
__global__ __launch_bounds__(1024) void bucket_scatter_kernel(
    const Edge3* __restrict__ stage, const int* __restrict__ start,
    Edge* __restrict__ packed)
{
    __shared__ int cur[BROWS];
    int b    = blockIdx.x;
    int row0 = b << BSHIFT;
    int rows = N_NODES - row0; if (rows > BROWS) rows = BROWS;
    int t = threadIdx.x;

    for (int i = t; i < rows; i += 1024) cur[i] = start[row0 + i];
    __syncthreads();

    int ebeg = start[row0];
    int eend = start[row0 + rows];
    for (int e = ebeg + t; e < eend; e += 1024) {
        Edge3 ed = stage[e];
        int pos = atomicAdd(&cur[ed.row - row0], 1);
        Edge p; p.col = ed.col; p.val = ed.val;
        packed[pos] = p;
    }
}

// ---------------------------------------------------------------------------
// CSR SpMM, fused with layer-sum update.
// 16 lanes per row, 4 dims per lane, register accumulation, no atomics.
// MLP: lane l loads edge jb+l (coalesced); broadcast all 16 (col,val) via
// __shfl into REGISTER ARRAYS first; then issue all 16 float4 gathers into
// xv[16] (static indexing, full unroll -> registers, rule #20); then 16
// FMAs. Gather addresses depend on no in-flight memory op -> 16 loads
// outstanding per wave. Inactive slots carry col=0/val=0: dummy gathers hit
// the x[0] line (L1), FMAs add 0 -> no guards, no divergence.
// __launch_bounds__(256,4): cap VGPR at 128 (16 waves/CU, no spill).
// ---------------------------------------------------------------------------
__global__ __launch_bounds__(256, 4) void spmm_csr_kernel(
    const float* __restrict__ x, const Edge* __restrict__ packed,
    const int* __restrict__ start,
    float* __restrict__ y, float* __restrict__ out, float scale)
{
    int g = blockIdx.x * (256 / 16) + (threadIdx.x >> 4);
    if (g >= N_NODES) return;
    const int lane16 = threadIdx.x & 15;
    const int d      = lane16 * 4;
    const int gbase  = threadIdx.x & 48;     // 16-group base lane within wave

    int beg = start[g];
    int end = start[g + 1];
    float4 acc = {0.f, 0.f, 0.f, 0.f};

    for (int jb = beg; jb < end; jb += 16) {
        Edge ed; ed.col = 0; ed.val = 0.f;
        if (jb + lane16 < end) ed = packed[jb + lane16];

        int   cols[16];
        float vals[16];
        #pragma unroll
        for (int k = 0; k < 16; ++k) {
            cols[k] = __shfl(ed.col, gbase + k, 64);
            vals[k] = __shfl(ed.val, gbase + k, 64);
        }

        float4 xv[16];
        #pragma unroll
        for (int k = 0; k < 16; ++k) {
            xv[k] = *reinterpret_cast<const float4*>(
                x + (size_t)cols[k] * EMB + d);
        }

        #pragma unroll
        for (int k = 0; k < 16; ++k) {
            acc.x += vals[k] * xv[k].x;
            acc.y += vals[k] * xv[k].y;
            acc.z += vals[k] * xv[k].z;
            acc.w += vals[k] * xv[k].w;
        }
    }

    *reinterpret_cast<float4*>(y + (size_t)g * EMB + d) = acc;

    float4 o = *reinterpret_cast<float4*>(out + (size_t)g * EMB + d);
    o.x = (o.x + acc.x) * scale;
    o.y = (o.y + acc.y) * scale;
    o.z = (o.z + acc.z) * scale;
    o.w = (o.w + acc.w) * scale;
    *reinterpret_cast<float4*>(out + (size_t)g * EMB + d) = o;
}

// ---------------------------------------------------------------------------
// Fallback path: edge-parallel atomics. Used only if ws too small for CSR.
// ---------------------------------------------------------------------------
__global__ __launch_bounds__(256) void spmm_atomic_kernel(
    const float* __restrict__ x, const float* __restrict__ val,
    const int* __restrict__ row, const int* __restrict__ col,
    float* __restrict__ y)
{
    int t = blockIdx.x * blockDim.x + threadIdx.x;
    int e = t >> 4;
    if (e >= N_EDGES) return;
    int d = (t & 15) * 4;
    int   r = row[e];
    int   c = col[e];
    float v = val[e];
    float4 xv = *reinterpret_cast<const float4*>(x + c * EMB + d);
    float* yp = y + r * EMB + d;
    unsafeAtomicAdd(yp + 0, v * xv.x);
    unsafeAtomicAdd(yp + 1, v * xv.y);
    unsafeAtomicAdd(yp + 2, v * xv.z);
    unsafeAtomicAdd(yp + 3, v * xv.w);
}

__global__ __launch_bounds__(256) void addscale_kernel(
    const float* __restrict__ xl, float* __restrict__ out, float scale)
{
    const int nt4 = N_NODES * EMB / 4;
    int i = blockIdx.x * blockDim.x + threadIdx.x;
    if (i >= nt4) return;
    float4 a = reinterpret_cast<float4*>(out)[i];
    float4 b = reinterpret_cast<const float4*>(xl)[i];
    a.x = (a.x + b.x) * scale;
    a.y = (a.y + b.y) * scale;
    a.z = (a.z + b.z) * scale;
    a.w = (a.w + b.w) * scale;
    reinterpret_cast<float4*>(out)[i] = a;
}

extern "C" void kernel_launch(void* const* d_in, const int* in_sizes, int n_in,
                              void* d_out, int out_size, void* d_ws, size_t ws_size,
                              hipStream_t stream) {
    const float* emb_user = (const float*)d_in[0];
    const float* emb_item = (const float*)d_in[1];
    const float* edge_val = (const float*)d_in[2];
    const int*   edge_row = (const int*)d_in[3];
    const int*   edge_col = (const int*)d_in[4];
    float* out = (float*)d_out;

    const size_t node_elems = (size_t)N_NODES * EMB;        // 19.2M floats
    char* ws = (char*)d_ws;

    // workspace layout (stage aliases bufB: dead until SpMM layer 0)
    const size_t off_bufA    = 0;
    const size_t off_bufB    = off_bufA + node_elems * sizeof(float);      // 76.8 MB
    const size_t off_packed  = off_bufB + node_elems * sizeof(float);      // 153.6 MB
    const size_t off_start   = off_packed + (size_t)N_EDGES * sizeof(Edge);// 193.6 MB
    const size_t off_cnt     = off_start + (N_NODES + 4) * sizeof(int);
    const size_t off_bsum    = off_cnt + N_NODES * sizeof(int);
    const size_t off_bpre    = off_bsum + SCAN_BLOCKS * sizeof(int);
    const size_t off_bcursor = off_bpre + SCAN_BLOCKS * sizeof(int);
    const size_t needed      = off_bcursor + (NBUCK + 4) * sizeof(int);    // ~196 MB

    float* bufA = (float*)(ws + off_bufA);
    float* bufB = (float*)(ws + off_bufB);

    const int nt4       = N_NODES * EMB / 4;
    const int el_blocks = (nt4 + 255) / 256;
    const int e_blocks  = (N_EDGES + 255) / 256;

    init_kernel<<<el_blocks, 256, 0, stream>>>(emb_user, emb_item, bufA, out);

    if (ws_size >= needed) {
        // ---- CSR path ----
        Edge*  packed  = (Edge*) (ws + off_packed);
        int*   start   = (int*)  (ws + off_start);
        int*   cnt     = (int*)  (ws + off_cnt);
        int*   bsum    = (int*)  (ws + off_bsum);
        int*   bpre    = (int*)  (ws + off_bpre);
        int*   bcursor = (int*)  (ws + off_bcursor);
        Edge3* stage   = (Edge3*)(ws + off_bufB);   // 60 MB inside bufB

        hipMemsetAsync(cnt, 0, N_NODES * sizeof(int), stream);
        count_kernel<<<e_blocks, 256, 0, stream>>>(edge_row, cnt);
        bsum_kernel<<<SCAN_BLOCKS, 256, 0, stream>>>(cnt, bsum);
        bscan_kernel<<<1, 1024, 0, stream>>>(bsum, bpre);
        scan_apply_kernel<<<SCAN_BLOCKS, 256, 0, stream>>>(cnt, bpre, start);
        binit_kernel<<<1, 256, 0, stream>>>(start, bcursor);
        const int bin_blocks = (N_EDGES + BIN_CHUNK - 1) / BIN_CHUNK;      // 1221
        bin_kernel<<<bin_blocks, 256, 0, stream>>>(edge_row, edge_col, edge_val,
                                                   bcursor, stage);
        bucket_scatter_kernel<<<NBUCK, 1024, 0, stream>>>(stage, start, packed);

        const int row_blocks = (N_NODES + 15) / 16;          // 16 rows / block
        float* cur = bufA;
        float* nxt = bufB;
        for (int layer = 0; layer < 3; ++layer) {
            spmm_csr_kernel<<<row_blocks, 256, 0, stream>>>(
                cur, packed, start, nxt, out,
                (layer == 2) ? 0.25f : 1.0f);
            float* tmp = cur; cur = nxt; nxt = tmp;
        }
    } else {
        // ---- fallback: atomic path (needs only 153.6 MB) ----
        const int ew_blocks = (N_EDGES * 16 + 255) / 256;
        float* cur = bufA;
        float* nxt = bufB;
        for (int layer = 0; layer < 3; ++layer) {
            hipMemsetAsync(nxt, 0, node_elems * sizeof(float), stream);
            spmm_atomic_kernel<<<ew_blocks, 256, 0, stream>>>(
                cur, edge_val, edge_row, edge_col, nxt);
            addscale_kernel<<<el_blocks, 256, 0, stream>>>(
                nxt, out, (layer == 2) ? 0.25f : 1.0f);
            float* tmp = cur; cur = nxt; nxt = tmp;
        }
    }
}

// Round 4
// 946.031 us; speedup vs baseline: 1.2474x; 1.2171x over previous
//
#include <hip/hip_runtime.h>

#define N_USERS 200000
#define N_ITEMS 100000
#define N_NODES 300000
#define EMB     64
#define N_EDGES 5000000

struct alignas(8) Edge { int col; float val; };
// 8 B staged record: rc = (rowLow11 << 19) | col  (col < 2^19, bucket-local row)
struct alignas(8) SRec { unsigned int rc; float val; };

#define BSHIFT 11
#define BROWS  (1 << BSHIFT)                               // 2048
#define NBUCK  ((N_NODES + BROWS - 1) >> BSHIFT)           // 147
#define CAP    40960                                       // >> mean 34133 (+37 sigma)
#define BIN_CHUNK 4096                                     // edges per bin block
#define COLMASK 0x7FFFFu

// ---------------------------------------------------------------------------
// Fused init + bin.
//  blocks [0, bin_blocks)          : bin 4096 edges -> stage[b*CAP + cursor]
//  blocks [bin_blocks, +el_blocks) : x = cat(user,item); out = x
// Bin needs NO precomputed CSR offsets: fixed-capacity bucket segments,
// bcursor[] zero-seeded. Stage order within bucket is arbitrary (scatter
// pass sorts by row via LDS counting-scan).
// ---------------------------------------------------------------------------
__global__ __launch_bounds__(256) void fused_init_bin_kernel(
    const float* __restrict__ user, const float* __restrict__ item,
    float* __restrict__ x, float* __restrict__ out,
    const int4* __restrict__ row4, const int4* __restrict__ col4,
    const float4* __restrict__ val4,
    int* __restrict__ bcursor, SRec* __restrict__ stage, int bin_blocks)
{
    int t = threadIdx.x;
    if ((int)blockIdx.x < bin_blocks) {
        __shared__ int hist[NBUCK];
        __shared__ int base_[NBUCK];
        const int Q = N_EDGES / 4;                    // int4 count (N_EDGES%4==0)
        long q0 = (long)blockIdx.x * (BIN_CHUNK / 4); // 1024 int4 / block

        for (int k = t; k < NBUCK; k += 256) hist[k] = 0;
        __syncthreads();

        int4 r[4]; int4 c[4]; float4 v[4]; bool ok[4];
        #pragma unroll
        for (int k = 0; k < 4; ++k) {
            long q = q0 + k * 256 + t;
            ok[k] = (q < Q);
            if (ok[k]) {
                r[k] = row4[q]; c[k] = col4[q]; v[k] = val4[q];
                atomicAdd(&hist[r[k].x >> BSHIFT], 1);
                atomicAdd(&hist[r[k].y >> BSHIFT], 1);
                atomicAdd(&hist[r[k].z >> BSHIFT], 1);
                atomicAdd(&hist[r[k].w >> BSHIFT], 1);
            }
        }
        __syncthreads();
        for (int k = t; k < NBUCK; k += 256) {
            int h = hist[k];
            base_[k] = h ? atomicAdd(&bcursor[k], h) : 0;
            hist[k] = 0;                               // reuse as local cursor
        }
        __syncthreads();
        #pragma unroll
        for (int k = 0; k < 4; ++k) {
            if (ok[k]) {
                int   rr[4] = {r[k].x, r[k].y, r[k].z, r[k].w};
                int   cc[4] = {c[k].x, c[k].y, c[k].z, c[k].w};
                float vv[4] = {v[k].x, v[k].y, v[k].z, v[k].w};
                #pragma unroll
                for (int j = 0; j < 4; ++j) {
                    int b   = rr[j] >> BSHIFT;
                    int pos = base_[b] + atomicAdd(&hist[b], 1);
                    SRec s;
                    s.rc  = ((unsigned)(rr[j] & (BROWS - 1)) << 19) | (unsigned)cc[j];
                    s.val = vv[j];
                    stage[(size_t)b * CAP + pos] = s;
                }
            }
        }
    } else {
        const int nu4 = N_USERS * EMB / 4;
        const int nt4 = N_NODES * EMB / 4;
        int i = ((int)blockIdx.x - bin_blocks) * 256 + t;
        if (i >= nt4) return;
        float4 vv = (i < nu4) ? reinterpret_cast<const float4*>(user)[i]
                              : reinterpret_cast<const float4*>(item)[i - nu4];
        reinterpret_cast<float4*>(x)[i]   = vv;
        reinterpret_cast<float4*>(out)[i] = vv;
    }
}

// ---------------------------------------------------------------------------
// Per-bucket: count rows in LDS -> LDS scan -> bucket base (prefix over 147
// sizes) -> write start[] -> scatter to packed. Replaces the entire
// count/bsum/bscan/scan_apply/binit/bucket_scatter chain.
// ---------------------------------------------------------------------------
__global__ __launch_bounds__(1024) void bucket_scan_scatter_kernel(
    const SRec* __restrict__ stage, const int* __restrict__ bsize,
    int* __restrict__ start, Edge* __restrict__ packed)
{
    __shared__ int sizes[NBUCK];
    __shared__ int cnt[BROWS];
    __shared__ int cur[BROWS];
    __shared__ int sc[1024];
    __shared__ int sbase;

    int b    = blockIdx.x;
    int t    = threadIdx.x;
    int row0 = b << BSHIFT;
    int rows = N_NODES - row0; if (rows > BROWS) rows = BROWS;

    if (t < NBUCK) sizes[t] = bsize[t];
    for (int i = t; i < BROWS; i += 1024) cnt[i] = 0;
    __syncthreads();
    if (t == 0) {                       // bucket base: serial prefix over LDS
        int s = 0;
        for (int k = 0; k < b; ++k) s += sizes[k];
        sbase = s;
    }
    __syncthreads();
    const int  base = sbase;
    const int  size = sizes[b];
    const SRec* seg = stage + (size_t)b * CAP;

    // pass A: per-row counts
    for (int e = t; e < size; e += 1024)
        atomicAdd(&cnt[seg[e].rc >> 19], 1);
    __syncthreads();

    // exclusive scan over 2048 counts (2 per thread + Hillis-Steele on 1024)
    int a0 = cnt[2 * t], a1 = cnt[2 * t + 1];
    int s01 = a0 + a1;
    sc[t] = s01;
    __syncthreads();
    for (int ofs = 1; ofs < 1024; ofs <<= 1) {
        int v = (t >= ofs) ? sc[t - ofs] : 0;
        __syncthreads();
        sc[t] += v;
        __syncthreads();
    }
    int ex = sc[t] - s01;
    cur[2 * t]     = base + ex;
    cur[2 * t + 1] = base + ex + a0;
    __syncthreads();

    for (int i = t; i < rows; i += 1024) start[row0 + i] = cur[i];
    if (b == NBUCK - 1 && t == 0) start[N_NODES] = N_EDGES;
    __syncthreads();

    // pass B: scatter (seg is L2-warm from pass A)
    for (int e = t; e < size; e += 1024) {
        SRec srec = seg[e];
        int pos = atomicAdd(&cur[srec.rc >> 19], 1);
        Edge p; p.col = (int)(srec.rc & COLMASK); p.val = srec.val;
        packed[pos] = p;
    }
}

// ---------------------------------------------------------------------------
// CSR SpMM, fused with layer-sum update (unchanged structure; R1/R2 showed
// it is memory-system-bound at ~3.9 TB/s L2-fill for random 256 B gathers,
// insensitive to MLP).
// ---------------------------------------------------------------------------
__global__ __launch_bounds__(256, 4) void spmm_csr_kernel(
    const float* __restrict__ x, const Edge* __restrict__ packed,
    const int* __restrict__ start,
    float* __restrict__ y, float* __restrict__ out, float scale)
{
    int g = blockIdx.x * (256 / 16) + (threadIdx.x >> 4);
    if (g >= N_NODES) return;
    const int lane16 = threadIdx.x & 15;
    const int d      = lane16 * 4;
    const int gbase  = threadIdx.x & 48;

    int beg = start[g];
    int end = start[g + 1];
    float4 acc = {0.f, 0.f, 0.f, 0.f};

    for (int jb = beg; jb < end; jb += 16) {
        Edge ed; ed.col = 0; ed.val = 0.f;
        if (jb + lane16 < end) ed = packed[jb + lane16];

        int   cols[16];
        float vals[16];
        #pragma unroll
        for (int k = 0; k < 16; ++k) {
            cols[k] = __shfl(ed.col, gbase + k, 64);
            vals[k] = __shfl(ed.val, gbase + k, 64);
        }

        float4 xv[16];
        #pragma unroll
        for (int k = 0; k < 16; ++k) {
            xv[k] = *reinterpret_cast<const float4*>(
                x + (size_t)cols[k] * EMB + d);
        }

        #pragma unroll
        for (int k = 0; k < 16; ++k) {
            acc.x += vals[k] * xv[k].x;
            acc.y += vals[k] * xv[k].y;
            acc.z += vals[k] * xv[k].z;
            acc.w += vals[k] * xv[k].w;
        }
    }

    *reinterpret_cast<float4*>(y + (size_t)g * EMB + d) = acc;

    float4 o = *reinterpret_cast<const float4*>(out + (size_t)g * EMB + d);
    o.x = (o.x + acc.x) * scale;
    o.y = (o.y + acc.y) * scale;
    o.z = (o.z + acc.z) * scale;
    o.w = (o.w + acc.w) * scale;
    *reinterpret_cast<float4*>(out + (size_t)g * EMB + d) = o;
}

// ---------------------------------------------------------------------------
// Fallback path (ws too small for CSR): unchanged.
// ---------------------------------------------------------------------------
__global__ __launch_bounds__(256) void init_kernel(
    const float* __restrict__ user, const float* __restrict__ item,
    float* __restrict__ x, float* __restrict__ out)
{
    const int nu4 = N_USERS * EMB / 4;
    const int nt4 = N_NODES * EMB / 4;
    int i = blockIdx.x * blockDim.x + threadIdx.x;
    if (i >= nt4) return;
    float4 v = (i < nu4) ? reinterpret_cast<const float4*>(user)[i]
                         : reinterpret_cast<const float4*>(item)[i - nu4];
    reinterpret_cast<float4*>(x)[i]   = v;
    reinterpret_cast<float4*>(out)[i] = v;
}

__global__ __launch_bounds__(256) void spmm_atomic_kernel(
    const float* __restrict__ x, const float* __restrict__ val,
    const int* __restrict__ row, const int* __restrict__ col,
    float* __restrict__ y)
{
    int t = blockIdx.x * blockDim.x + threadIdx.x;
    int e = t >> 4;
    if (e >= N_EDGES) return;
    int d = (t & 15) * 4;
    int   r = row[e];
    int   c = col[e];
    float v = val[e];
    float4 xv = *reinterpret_cast<const float4*>(x + c * EMB + d);
    float* yp = y + r * EMB + d;
    unsafeAtomicAdd(yp + 0, v * xv.x);
    unsafeAtomicAdd(yp + 1, v * xv.y);
    unsafeAtomicAdd(yp + 2, v * xv.z);
    unsafeAtomicAdd(yp + 3, v * xv.w);
}

__global__ __launch_bounds__(256) void addscale_kernel(
    const float* __restrict__ xl, float* __restrict__ out, float scale)
{
    const int nt4 = N_NODES * EMB / 4;
    int i = blockIdx.x * blockDim.x + threadIdx.x;
    if (i >= nt4) return;
    float4 a = reinterpret_cast<float4*>(out)[i];
    float4 b = reinterpret_cast<const float4*>(xl)[i];
    a.x = (a.x + b.x) * scale;
    a.y = (a.y + b.y) * scale;
    a.z = (a.z + b.z) * scale;
    a.w = (a.w + b.w) * scale;
    reinterpret_cast<float4*>(out)[i] = a;
}

extern "C" void kernel_launch(void* const* d_in, const int* in_sizes, int n_in,
                              void* d_out, int out_size, void* d_ws, size_t ws_size,
                              hipStream_t stream) {
    const float* emb_user = (const float*)d_in[0];
    const float* emb_item = (const float*)d_in[1];
    const float* edge_val = (const float*)d_in[2];
    const int*   edge_row = (const int*)d_in[3];
    const int*   edge_col = (const int*)d_in[4];
    float* out = (float*)d_out;

    const size_t node_elems = (size_t)N_NODES * EMB;        // 19.2M floats
    char* ws = (char*)d_ws;

    // workspace layout (stage aliases bufB: dead until SpMM layer 0)
    const size_t off_bufA    = 0;
    const size_t off_bufB    = off_bufA + node_elems * sizeof(float);      // 76.8 MB
    const size_t off_packed  = off_bufB + node_elems * sizeof(float);      // 153.6 MB
    const size_t off_start   = off_packed + (size_t)N_EDGES * sizeof(Edge);// 193.6 MB
    const size_t off_bcursor = off_start + (N_NODES + 4) * sizeof(int);
    const size_t needed      = off_bcursor + (NBUCK + 4) * sizeof(int);    // ~195 MB

    float* bufA = (float*)(ws + off_bufA);
    float* bufB = (float*)(ws + off_bufB);

    const int nt4       = N_NODES * EMB / 4;
    const int el_blocks = (nt4 + 255) / 256;                 // 18750
    const int e_blocks  = (N_EDGES + 255) / 256;

    // stage capacity check: NBUCK * CAP * 8 B = 48.2 MB <= bufB (76.8 MB)
    static_assert((size_t)NBUCK * CAP * sizeof(SRec) <= (size_t)N_NODES * EMB * sizeof(float),
                  "stage must fit in bufB");

    if (ws_size >= needed) {
        // ---- CSR path ----
        Edge* packed  = (Edge*)(ws + off_packed);
        int*  start   = (int*) (ws + off_start);
        int*  bcursor = (int*) (ws + off_bcursor);
        SRec* stage   = (SRec*)(ws + off_bufB);

        hipMemsetAsync(bcursor, 0, (NBUCK + 4) * sizeof(int), stream);

        const int bin_blocks = (N_EDGES + BIN_CHUNK - 1) / BIN_CHUNK;      // 1221
        fused_init_bin_kernel<<<bin_blocks + el_blocks, 256, 0, stream>>>(
            emb_user, emb_item, bufA, out,
            (const int4*)edge_row, (const int4*)edge_col, (const float4*)edge_val,
            bcursor, stage, bin_blocks);

        bucket_scan_scatter_kernel<<<NBUCK, 1024, 0, stream>>>(
            stage, bcursor, start, packed);

        const int row_blocks = (N_NODES + 15) / 16;
        float* cur = bufA;
        float* nxt = bufB;
        for (int layer = 0; layer < 3; ++layer) {
            spmm_csr_kernel<<<row_blocks, 256, 0, stream>>>(
                cur, packed, start, nxt, out,
                (layer == 2) ? 0.25f : 1.0f);
            float* tmp = cur; cur = nxt; nxt = tmp;
        }
    } else {
        // ---- fallback: atomic path (needs only 153.6 MB) ----
        init_kernel<<<el_blocks, 256, 0, stream>>>(emb_user, emb_item, bufA, out);
        const int ew_blocks = (N_EDGES * 16 + 255) / 256;
        float* cur = bufA;
        float* nxt = bufB;
        for (int layer = 0; layer < 3; ++layer) {
            hipMemsetAsync(nxt, 0, node_elems * sizeof(float), stream);
            spmm_atomic_kernel<<<ew_blocks, 256, 0, stream>>>(
                cur, edge_val, edge_row, edge_col, nxt);
            addscale_kernel<<<el_blocks, 256, 0, stream>>>(
                nxt, out, (layer == 2) ? 0.25f : 1.0f);
            float* tmp = cur; cur = nxt; nxt = tmp;
        }
    }
}

// Round 5
// 925.212 us; speedup vs baseline: 1.2754x; 1.0225x over previous
//
#include <hip/hip_runtime.h>

#define N_USERS 200000
#define N_ITEMS 100000
#define N_NODES 300000
#define EMB     64
#define N_EDGES 5000000

typedef float f32x4 __attribute__((ext_vector_type(4)));   // nt-builtin-compatible

struct alignas(8) Edge { int col; float val; };
// 8 B staged record: rc = (rowLow11 << 19) | col  (col < 2^19, bucket-local row)
struct alignas(8) SRec { unsigned int rc; float val; };

#define BSHIFT 11
#define BROWS  (1 << BSHIFT)                               // 2048
#define NBUCK  ((N_NODES + BROWS - 1) >> BSHIFT)           // 147
#define CAP    40960                                       // >> mean 34133 (+37 sigma)
#define BIN_CHUNK 4096                                     // edges per bin block
#define COLMASK 0x7FFFFu

// ---------------------------------------------------------------------------
// Fused init + bin.
//  blocks [0, bin_blocks)          : bin 4096 edges -> stage[b*CAP + cursor]
//  blocks [bin_blocks, +el_blocks) : x = cat(user,item); out = x
// out store is NONTEMPORAL: out is a pure stream (read once per spmm layer),
// keeping it out of L3 preserves residency for the gather table x.
// ---------------------------------------------------------------------------
__global__ __launch_bounds__(256) void fused_init_bin_kernel(
    const float* __restrict__ user, const float* __restrict__ item,
    float* __restrict__ x, float* __restrict__ out,
    const int4* __restrict__ row4, const int4* __restrict__ col4,
    const float4* __restrict__ val4,
    int* __restrict__ bcursor, SRec* __restrict__ stage, int bin_blocks)
{
    int t = threadIdx.x;
    if ((int)blockIdx.x < bin_blocks) {
        __shared__ int hist[NBUCK];
        __shared__ int base_[NBUCK];
        const int Q = N_EDGES / 4;                    // int4 count (N_EDGES%4==0)
        long q0 = (long)blockIdx.x * (BIN_CHUNK / 4); // 1024 int4 / block

        for (int k = t; k < NBUCK; k += 256) hist[k] = 0;
        __syncthreads();

        int4 r[4]; int4 c[4]; float4 v[4]; bool ok[4];
        #pragma unroll
        for (int k = 0; k < 4; ++k) {
            long q = q0 + k * 256 + t;
            ok[k] = (q < Q);
            if (ok[k]) {
                r[k] = row4[q]; c[k] = col4[q]; v[k] = val4[q];
                atomicAdd(&hist[r[k].x >> BSHIFT], 1);
                atomicAdd(&hist[r[k].y >> BSHIFT], 1);
                atomicAdd(&hist[r[k].z >> BSHIFT], 1);
                atomicAdd(&hist[r[k].w >> BSHIFT], 1);
            }
        }
        __syncthreads();
        for (int k = t; k < NBUCK; k += 256) {
            int h = hist[k];
            base_[k] = h ? atomicAdd(&bcursor[k], h) : 0;
            hist[k] = 0;                               // reuse as local cursor
        }
        __syncthreads();
        #pragma unroll
        for (int k = 0; k < 4; ++k) {
            if (ok[k]) {
                int   rr[4] = {r[k].x, r[k].y, r[k].z, r[k].w};
                int   cc[4] = {c[k].x, c[k].y, c[k].z, c[k].w};
                float vv[4] = {v[k].x, v[k].y, v[k].z, v[k].w};
                #pragma unroll
                for (int j = 0; j < 4; ++j) {
                    int b   = rr[j] >> BSHIFT;
                    int pos = base_[b] + atomicAdd(&hist[b], 1);
                    SRec s;
                    s.rc  = ((unsigned)(rr[j] & (BROWS - 1)) << 19) | (unsigned)cc[j];
                    s.val = vv[j];
                    stage[(size_t)b * CAP + pos] = s;
                }
            }
        }
    } else {
        const int nu4 = N_USERS * EMB / 4;
        const int nt4 = N_NODES * EMB / 4;
        int i = ((int)blockIdx.x - bin_blocks) * 256 + t;
        if (i >= nt4) return;
        float4 vv = (i < nu4) ? reinterpret_cast<const float4*>(user)[i]
                              : reinterpret_cast<const float4*>(item)[i - nu4];
        reinterpret_cast<float4*>(x)[i] = vv;          // x: cacheable (gather table)
        f32x4 ov = {vv.x, vv.y, vv.z, vv.w};
        __builtin_nontemporal_store(ov, reinterpret_cast<f32x4*>(out) + i);
    }
}

// ---------------------------------------------------------------------------
// Per-bucket: count rows in LDS -> LDS scan -> bucket base (prefix over 147
// sizes) -> write start[] -> scatter to packed.
// ---------------------------------------------------------------------------
__global__ __launch_bounds__(1024) void bucket_scan_scatter_kernel(
    const SRec* __restrict__ stage, const int* __restrict__ bsize,
    int* __restrict__ start, Edge* __restrict__ packed)
{
    __shared__ int sizes[NBUCK];
    __shared__ int cnt[BROWS];
    __shared__ int cur[BROWS];
    __shared__ int sc[1024];
    __shared__ int sbase;

    int b    = blockIdx.x;
    int t    = threadIdx.x;
    int row0 = b << BSHIFT;
    int rows = N_NODES - row0; if (rows > BROWS) rows = BROWS;

    if (t < NBUCK) sizes[t] = bsize[t];
    for (int i = t; i < BROWS; i += 1024) cnt[i] = 0;
    __syncthreads();
    if (t == 0) {                       // bucket base: serial prefix over LDS
        int s = 0;
        for (int k = 0; k < b; ++k) s += sizes[k];
        sbase = s;
    }
    __syncthreads();
    const int  base = sbase;
    const int  size = sizes[b];
    const SRec* seg = stage + (size_t)b * CAP;

    // pass A: per-row counts
    for (int e = t; e < size; e += 1024)
        atomicAdd(&cnt[seg[e].rc >> 19], 1);
    __syncthreads();

    // exclusive scan over 2048 counts (2 per thread + Hillis-Steele on 1024)
    int a0 = cnt[2 * t], a1 = cnt[2 * t + 1];
    int s01 = a0 + a1;
    sc[t] = s01;
    __syncthreads();
    for (int ofs = 1; ofs < 1024; ofs <<= 1) {
        int v = (t >= ofs) ? sc[t - ofs] : 0;
        __syncthreads();
        sc[t] += v;
        __syncthreads();
    }
    int ex = sc[t] - s01;
    cur[2 * t]     = base + ex;
    cur[2 * t + 1] = base + ex + a0;
    __syncthreads();

    for (int i = t; i < rows; i += 1024) start[row0 + i] = cur[i];
    if (b == NBUCK - 1 && t == 0) start[N_NODES] = N_EDGES;
    __syncthreads();

    // pass B: scatter (seg is L2-warm from pass A)
    for (int e = t; e < size; e += 1024) {
        SRec srec = seg[e];
        int pos = atomicAdd(&cur[srec.rc >> 19], 1);
        Edge p; p.col = (int)(srec.rc & COLMASK); p.val = srec.val;
        packed[pos] = p;
    }
}

// ---------------------------------------------------------------------------
// CSR SpMM, fused with layer-sum update.
// R1/R2: insensitive to MLP at fixed 667 MB FETCH -> the limit is L3 misses
// on the x gathers (working set 270 MB > 256 MB L3). This round: `out`
// traffic is nontemporal (pure stream, zero reuse), y store skipped on the
// last layer -> x + y + packed = 193 MB fits L3; gathers should become L3
// hits and FETCH_SIZE should collapse.
// ---------------------------------------------------------------------------
__global__ __launch_bounds__(256, 4) void spmm_csr_kernel(
    const float* __restrict__ x, const Edge* __restrict__ packed,
    const int* __restrict__ start,
    float* __restrict__ y, float* __restrict__ out, float scale, int write_y)
{
    int g = blockIdx.x * (256 / 16) + (threadIdx.x >> 4);
    if (g >= N_NODES) return;
    const int lane16 = threadIdx.x & 15;
    const int d      = lane16 * 4;
    const int gbase  = threadIdx.x & 48;

    int beg = start[g];
    int end = start[g + 1];
    float4 acc = {0.f, 0.f, 0.f, 0.f};

    for (int jb = beg; jb < end; jb += 16) {
        Edge ed; ed.col = 0; ed.val = 0.f;
        if (jb + lane16 < end) ed = packed[jb + lane16];

        int   cols[16];
        float vals[16];
        #pragma unroll
        for (int k = 0; k < 16; ++k) {
            cols[k] = __shfl(ed.col, gbase + k, 64);
            vals[k] = __shfl(ed.val, gbase + k, 64);
        }

        float4 xv[16];
        #pragma unroll
        for (int k = 0; k < 16; ++k) {
            xv[k] = *reinterpret_cast<const float4*>(
                x + (size_t)cols[k] * EMB + d);
        }

        #pragma unroll
        for (int k = 0; k < 16; ++k) {
            acc.x += vals[k] * xv[k].x;
            acc.y += vals[k] * xv[k].y;
            acc.z += vals[k] * xv[k].z;
            acc.w += vals[k] * xv[k].w;
        }
    }

    if (write_y)
        *reinterpret_cast<float4*>(y + (size_t)g * EMB + d) = acc;

    f32x4* op = reinterpret_cast<f32x4*>(out + (size_t)g * EMB + d);
    f32x4 o = __builtin_nontemporal_load(op);
    o.x = (o.x + acc.x) * scale;
    o.y = (o.y + acc.y) * scale;
    o.z = (o.z + acc.z) * scale;
    o.w = (o.w + acc.w) * scale;
    __builtin_nontemporal_store(o, op);
}

// ---------------------------------------------------------------------------
// Fallback path (ws too small for CSR): unchanged.
// ---------------------------------------------------------------------------
__global__ __launch_bounds__(256) void init_kernel(
    const float* __restrict__ user, const float* __restrict__ item,
    float* __restrict__ x, float* __restrict__ out)
{
    const int nu4 = N_USERS * EMB / 4;
    const int nt4 = N_NODES * EMB / 4;
    int i = blockIdx.x * blockDim.x + threadIdx.x;
    if (i >= nt4) return;
    float4 v = (i < nu4) ? reinterpret_cast<const float4*>(user)[i]
                         : reinterpret_cast<const float4*>(item)[i - nu4];
    reinterpret_cast<float4*>(x)[i]   = v;
    reinterpret_cast<float4*>(out)[i] = v;
}

__global__ __launch_bounds__(256) void spmm_atomic_kernel(
    const float* __restrict__ x, const float* __restrict__ val,
    const int* __restrict__ row, const int* __restrict__ col,
    float* __restrict__ y)
{
    int t = blockIdx.x * blockDim.x + threadIdx.x;
    int e = t >> 4;
    if (e >= N_EDGES) return;
    int d = (t & 15) * 4;
    int   r = row[e];
    int   c = col[e];
    float v = val[e];
    float4 xv = *reinterpret_cast<const float4*>(x + c * EMB + d);
    float* yp = y + r * EMB + d;
    unsafeAtomicAdd(yp + 0, v * xv.x);
    unsafeAtomicAdd(yp + 1, v * xv.y);
    unsafeAtomicAdd(yp + 2, v * xv.z);
    unsafeAtomicAdd(yp + 3, v * xv.w);
}

__global__ __launch_bounds__(256) void addscale_kernel(
    const float* __restrict__ xl, float* __restrict__ out, float scale)
{
    const int nt4 = N_NODES * EMB / 4;
    int i = blockIdx.x * blockDim.x + threadIdx.x;
    if (i >= nt4) return;
    float4 a = reinterpret_cast<float4*>(out)[i];
    float4 b = reinterpret_cast<const float4*>(xl)[i];
    a.x = (a.x + b.x) * scale;
    a.y = (a.y + b.y) * scale;
    a.z = (a.z + b.z) * scale;
    a.w = (a.w + b.w) * scale;
    reinterpret_cast<float4*>(out)[i] = a;
}

extern "C" void kernel_launch(void* const* d_in, const int* in_sizes, int n_in,
                              void* d_out, int out_size, void* d_ws, size_t ws_size,
                              hipStream_t stream) {
    const float* emb_user = (const float*)d_in[0];
    const float* emb_item = (const float*)d_in[1];
    const float* edge_val = (const float*)d_in[2];
    const int*   edge_row = (const int*)d_in[3];
    const int*   edge_col = (const int*)d_in[4];
    float* out = (float*)d_out;

    const size_t node_elems = (size_t)N_NODES * EMB;        // 19.2M floats
    char* ws = (char*)d_ws;

    // workspace layout (stage aliases bufB: dead until SpMM layer 0)
    const size_t off_bufA    = 0;
    const size_t off_bufB    = off_bufA + node_elems * sizeof(float);      // 76.8 MB
    const size_t off_packed  = off_bufB + node_elems * sizeof(float);      // 153.6 MB
    const size_t off_start   = off_packed + (size_t)N_EDGES * sizeof(Edge);// 193.6 MB
    const size_t off_bcursor = off_start + (N_NODES + 4) * sizeof(int);
    const size_t needed      = off_bcursor + (NBUCK + 4) * sizeof(int);    // ~195 MB

    float* bufA = (float*)(ws + off_bufA);
    float* bufB = (float*)(ws + off_bufB);

    const int nt4       = N_NODES * EMB / 4;
    const int el_blocks = (nt4 + 255) / 256;                 // 18750
    const int e_blocks  = (N_EDGES + 255) / 256;

    // stage capacity check: NBUCK * CAP * 8 B = 48.2 MB <= bufB (76.8 MB)
    static_assert((size_t)NBUCK * CAP * sizeof(SRec) <= (size_t)N_NODES * EMB * sizeof(float),
                  "stage must fit in bufB");

    if (ws_size >= needed) {
        // ---- CSR path ----
        Edge* packed  = (Edge*)(ws + off_packed);
        int*  start   = (int*) (ws + off_start);
        int*  bcursor = (int*) (ws + off_bcursor);
        SRec* stage   = (SRec*)(ws + off_bufB);

        hipMemsetAsync(bcursor, 0, (NBUCK + 4) * sizeof(int), stream);

        const int bin_blocks = (N_EDGES + BIN_CHUNK - 1) / BIN_CHUNK;      // 1221
        fused_init_bin_kernel<<<bin_blocks + el_blocks, 256, 0, stream>>>(
            emb_user, emb_item, bufA, out,
            (const int4*)edge_row, (const int4*)edge_col, (const float4*)edge_val,
            bcursor, stage, bin_blocks);

        bucket_scan_scatter_kernel<<<NBUCK, 1024, 0, stream>>>(
            stage, bcursor, start, packed);

        const int row_blocks = (N_NODES + 15) / 16;
        float* cur = bufA;
        float* nxt = bufB;
        for (int layer = 0; layer < 3; ++layer) {
            spmm_csr_kernel<<<row_blocks, 256, 0, stream>>>(
                cur, packed, start, nxt, out,
                (layer == 2) ? 0.25f : 1.0f,
                (layer == 2) ? 0 : 1);
            float* tmp = cur; cur = nxt; nxt = tmp;
        }
    } else {
        // ---- fallback: atomic path (needs only 153.6 MB) ----
        init_kernel<<<el_blocks, 256, 0, stream>>>(emb_user, emb_item, bufA, out);
        const int ew_blocks = (N_EDGES * 16 + 255) / 256;
        float* cur = bufA;
        float* nxt = bufB;
        for (int layer = 0; layer < 3; ++layer) {
            hipMemsetAsync(nxt, 0, node_elems * sizeof(float), stream);
            spmm_atomic_kernel<<<ew_blocks, 256, 0, stream>>>(
                cur, edge_val, edge_row, edge_col, nxt);
            addscale_kernel<<<el_blocks, 256, 0, stream>>>(
                nxt, out, (layer == 2) ? 0.25f : 1.0f);
            float* tmp = cur; cur = nxt; nxt = tmp;
        }
    }
}

// Round 6
// 655.933 us; speedup vs baseline: 1.7990x; 1.4105x over previous
//
#include <hip/hip_runtime.h>

#define N_USERS 200000
#define N_ITEMS 100000
#define N_NODES 300000
#define EMB     64
#define N_EDGES 5000000

typedef float f32x4 __attribute__((ext_vector_type(4)));   // nt-builtin-compatible
typedef _Float16 f16;
typedef f16 f16x4 __attribute__((ext_vector_type(4)));     // 8 B gather granule

struct alignas(8) Edge { int col; float val; };
// 8 B staged record: rc = (rowLow11 << 19) | col  (col < 2^19, bucket-local row)
struct alignas(8) SRec { unsigned int rc; float val; };

#define BSHIFT 11
#define BROWS  (1 << BSHIFT)                               // 2048
#define NBUCK  ((N_NODES + BROWS - 1) >> BSHIFT)           // 147
#define CAP    40960                                       // >> mean 34013 (+large margin)
#define BIN_CHUNK 16384                                    // edges per bin block (2-pass)
#define COLMASK 0x7FFFFu

// ---------------------------------------------------------------------------
// Fused init + bin.
//  blocks [0, bin_blocks)          : TWO-PASS bin of 16384 edges/block:
//      pass A: count into LDS hist -> single cursor claim per bucket
//      pass B: re-read edges (L2-warm) -> scatter line-dense ~890 B runs
//    (R5 and earlier: 4096-edge blocks claimed 224 B sub-line runs -> cross-
//     XCD false sharing on the 40 MB stage write.)
//  blocks [bin_blocks, +el_blocks) : x0 = fp16(cat(user,item)); out = fp32 x0
// ---------------------------------------------------------------------------
__global__ __launch_bounds__(256) void fused_init_bin_kernel(
    const float* __restrict__ user, const float* __restrict__ item,
    f16* __restrict__ x, float* __restrict__ out,
    const int4* __restrict__ row4, const int4* __restrict__ col4,
    const float4* __restrict__ val4,
    int* __restrict__ bcursor, SRec* __restrict__ stage, int bin_blocks)
{
    int t = threadIdx.x;
    if ((int)blockIdx.x < bin_blocks) {
        __shared__ int hist[NBUCK];
        __shared__ int base_[NBUCK];
        const int Q = N_EDGES / 4;                    // int4 count (N_EDGES%4==0)
        long q0 = (long)blockIdx.x * (BIN_CHUNK / 4); // 4096 int4 / block

        for (int k = t; k < NBUCK; k += 256) hist[k] = 0;
        __syncthreads();

        // pass A: count 16K edges
        #pragma unroll
        for (int k = 0; k < 16; ++k) {
            long q = q0 + k * 256 + t;
            if (q < Q) {
                int4 r = row4[q];
                atomicAdd(&hist[r.x >> BSHIFT], 1);
                atomicAdd(&hist[r.y >> BSHIFT], 1);
                atomicAdd(&hist[r.z >> BSHIFT], 1);
                atomicAdd(&hist[r.w >> BSHIFT], 1);
            }
        }
        __syncthreads();
        // one claim per bucket for the whole 16K chunk -> dense runs
        for (int k = t; k < NBUCK; k += 256) {
            int h = hist[k];
            base_[k] = h ? atomicAdd(&bcursor[k], h) : 0;
            hist[k] = 0;                               // reuse as local cursor
        }
        __syncthreads();
        // pass B: re-read (rows L2-warm) and scatter
        #pragma unroll
        for (int k = 0; k < 16; ++k) {
            long q = q0 + k * 256 + t;
            if (q < Q) {
                int4 r = row4[q]; int4 c = col4[q]; float4 v = val4[q];
                int   rr[4] = {r.x, r.y, r.z, r.w};
                int   cc[4] = {c.x, c.y, c.z, c.w};
                float vv[4] = {v.x, v.y, v.z, v.w};
                #pragma unroll
                for (int j = 0; j < 4; ++j) {
                    int b   = rr[j] >> BSHIFT;
                    int pos = base_[b] + atomicAdd(&hist[b], 1);
                    SRec s;
                    s.rc  = ((unsigned)(rr[j] & (BROWS - 1)) << 19) | (unsigned)cc[j];
                    s.val = vv[j];
                    stage[(size_t)b * CAP + pos] = s;
                }
            }
        }
    } else {
        const int nu4 = N_USERS * EMB / 4;
        const int nt4 = N_NODES * EMB / 4;
        int i = ((int)blockIdx.x - bin_blocks) * 256 + t;
        if (i >= nt4) return;
        float4 vv = (i < nu4) ? reinterpret_cast<const float4*>(user)[i]
                              : reinterpret_cast<const float4*>(item)[i - nu4];
        f16x4 hx = {(f16)vv.x, (f16)vv.y, (f16)vv.z, (f16)vv.w};
        reinterpret_cast<f16x4*>(x)[i] = hx;           // gather table: fp16
        f32x4 ov = {vv.x, vv.y, vv.z, vv.w};
        __builtin_nontemporal_store(ov, reinterpret_cast<f32x4*>(out) + i);
    }
}

// ---------------------------------------------------------------------------
// Per-bucket: count rows in LDS -> LDS scan -> bucket base (prefix over 147
// sizes) -> write start[] -> scatter to packed.
// ---------------------------------------------------------------------------
__global__ __launch_bounds__(1024) void bucket_scan_scatter_kernel(
    const SRec* __restrict__ stage, const int* __restrict__ bsize,
    int* __restrict__ start, Edge* __restrict__ packed)
{
    __shared__ int sizes[NBUCK];
    __shared__ int cnt[BROWS];
    __shared__ int cur[BROWS];
    __shared__ int sc[1024];
    __shared__ int sbase;

    int b    = blockIdx.x;
    int t    = threadIdx.x;
    int row0 = b << BSHIFT;
    int rows = N_NODES - row0; if (rows > BROWS) rows = BROWS;

    if (t < NBUCK) sizes[t] = bsize[t];
    for (int i = t; i < BROWS; i += 1024) cnt[i] = 0;
    __syncthreads();
    if (t == 0) {                       // bucket base: serial prefix over LDS
        int s = 0;
        for (int k = 0; k < b; ++k) s += sizes[k];
        sbase = s;
    }
    __syncthreads();
    const int  base = sbase;
    const int  size = sizes[b];
    const SRec* seg = stage + (size_t)b * CAP;

    // pass A: per-row counts
    for (int e = t; e < size; e += 1024)
        atomicAdd(&cnt[seg[e].rc >> 19], 1);
    __syncthreads();

    // exclusive scan over 2048 counts (2 per thread + Hillis-Steele on 1024)
    int a0 = cnt[2 * t], a1 = cnt[2 * t + 1];
    int s01 = a0 + a1;
    sc[t] = s01;
    __syncthreads();
    for (int ofs = 1; ofs < 1024; ofs <<= 1) {
        int v = (t >= ofs) ? sc[t - ofs] : 0;
        __syncthreads();
        sc[t] += v;
        __syncthreads();
    }
    int ex = sc[t] - s01;
    cur[2 * t]     = base + ex;
    cur[2 * t + 1] = base + ex + a0;
    __syncthreads();

    for (int i = t; i < rows; i += 1024) start[row0 + i] = cur[i];
    if (b == NBUCK - 1 && t == 0) start[N_NODES] = N_EDGES;
    __syncthreads();

    // pass B: scatter (seg is L2-warm from pass A)
    for (int e = t; e < size; e += 1024) {
        SRec srec = seg[e];
        int pos = atomicAdd(&cur[srec.rc >> 19], 1);
        Edge p; p.col = (int)(srec.rc & COLMASK); p.val = srec.val;
        packed[pos] = p;
    }
}

// ---------------------------------------------------------------------------
// CSR SpMM over fp16 tables, fused with fp32 layer-sum update.
// R1/R2/R5 established: miss-path-byte-throughput-bound (~3.9 TB/s at 667 MB),
// insensitive to MLP and nt hints. This round halves the gathered bytes
// (fp16 rows = 128 B) and halves the table footprint (38.4 MB -> better
// L2/L3 hit rates). Accumulation stays fp32; out stays fp32.
// ---------------------------------------------------------------------------
__global__ __launch_bounds__(256, 4) void spmm_csr_kernel(
    const f16* __restrict__ x, const Edge* __restrict__ packed,
    const int* __restrict__ start,
    f16* __restrict__ y, float* __restrict__ out, float scale, int write_y)
{
    int g = blockIdx.x * (256 / 16) + (threadIdx.x >> 4);
    if (g >= N_NODES) return;
    const int lane16 = threadIdx.x & 15;
    const int d      = lane16 * 4;
    const int gbase  = threadIdx.x & 48;

    int beg = start[g];
    int end = start[g + 1];
    float4 acc = {0.f, 0.f, 0.f, 0.f};

    for (int jb = beg; jb < end; jb += 16) {
        Edge ed; ed.col = 0; ed.val = 0.f;
        if (jb + lane16 < end) ed = packed[jb + lane16];

        int   cols[16];
        float vals[16];
        #pragma unroll
        for (int k = 0; k < 16; ++k) {
            cols[k] = __shfl(ed.col, gbase + k, 64);
            vals[k] = __shfl(ed.val, gbase + k, 64);
        }

        f16x4 xv[16];
        #pragma unroll
        for (int k = 0; k < 16; ++k) {
            xv[k] = *reinterpret_cast<const f16x4*>(
                x + (size_t)cols[k] * EMB + d);
        }

        #pragma unroll
        for (int k = 0; k < 16; ++k) {
            acc.x += vals[k] * (float)xv[k].x;
            acc.y += vals[k] * (float)xv[k].y;
            acc.z += vals[k] * (float)xv[k].z;
            acc.w += vals[k] * (float)xv[k].w;
        }
    }

    if (write_y) {
        f16x4 hy = {(f16)acc.x, (f16)acc.y, (f16)acc.z, (f16)acc.w};
        *reinterpret_cast<f16x4*>(y + (size_t)g * EMB + d) = hy;
    }

    f32x4* op = reinterpret_cast<f32x4*>(out + (size_t)g * EMB + d);
    f32x4 o = __builtin_nontemporal_load(op);
    o.x = (o.x + acc.x) * scale;
    o.y = (o.y + acc.y) * scale;
    o.z = (o.z + acc.z) * scale;
    o.w = (o.w + acc.w) * scale;
    __builtin_nontemporal_store(o, op);
}

// ---------------------------------------------------------------------------
// Fallback path (ws too small for CSR): unchanged fp32 atomic path.
// ---------------------------------------------------------------------------
__global__ __launch_bounds__(256) void init_kernel(
    const float* __restrict__ user, const float* __restrict__ item,
    float* __restrict__ x, float* __restrict__ out)
{
    const int nu4 = N_USERS * EMB / 4;
    const int nt4 = N_NODES * EMB / 4;
    int i = blockIdx.x * blockDim.x + threadIdx.x;
    if (i >= nt4) return;
    float4 v = (i < nu4) ? reinterpret_cast<const float4*>(user)[i]
                         : reinterpret_cast<const float4*>(item)[i - nu4];
    reinterpret_cast<float4*>(x)[i]   = v;
    reinterpret_cast<float4*>(out)[i] = v;
}

__global__ __launch_bounds__(256) void spmm_atomic_kernel(
    const float* __restrict__ x, const float* __restrict__ val,
    const int* __restrict__ row, const int* __restrict__ col,
    float* __restrict__ y)
{
    int t = blockIdx.x * blockDim.x + threadIdx.x;
    int e = t >> 4;
    if (e >= N_EDGES) return;
    int d = (t & 15) * 4;
    int   r = row[e];
    int   c = col[e];
    float v = val[e];
    float4 xv = *reinterpret_cast<const float4*>(x + c * EMB + d);
    float* yp = y + r * EMB + d;
    unsafeAtomicAdd(yp + 0, v * xv.x);
    unsafeAtomicAdd(yp + 1, v * xv.y);
    unsafeAtomicAdd(yp + 2, v * xv.z);
    unsafeAtomicAdd(yp + 3, v * xv.w);
}

__global__ __launch_bounds__(256) void addscale_kernel(
    const float* __restrict__ xl, float* __restrict__ out, float scale)
{
    const int nt4 = N_NODES * EMB / 4;
    int i = blockIdx.x * blockDim.x + threadIdx.x;
    if (i >= nt4) return;
    float4 a = reinterpret_cast<float4*>(out)[i];
    float4 b = reinterpret_cast<const float4*>(xl)[i];
    a.x = (a.x + b.x) * scale;
    a.y = (a.y + b.y) * scale;
    a.z = (a.z + b.z) * scale;
    a.w = (a.w + b.w) * scale;
    reinterpret_cast<float4*>(out)[i] = a;
}

extern "C" void kernel_launch(void* const* d_in, const int* in_sizes, int n_in,
                              void* d_out, int out_size, void* d_ws, size_t ws_size,
                              hipStream_t stream) {
    const float* emb_user = (const float*)d_in[0];
    const float* emb_item = (const float*)d_in[1];
    const float* edge_val = (const float*)d_in[2];
    const int*   edge_row = (const int*)d_in[3];
    const int*   edge_col = (const int*)d_in[4];
    float* out = (float*)d_out;

    const size_t node_elems = (size_t)N_NODES * EMB;        // 19.2M elems
    char* ws = (char*)d_ws;

    // workspace layout (regions keep fp32-era sizes; fp16 buffers use half).
    // stage (48.2 MB) aliases the bufB region: dead before SpMM layer 0
    // overwrites it with y (38.4 MB fp16).
    const size_t off_bufA    = 0;
    const size_t off_bufB    = off_bufA + node_elems * sizeof(float);      // 76.8 MB
    const size_t off_packed  = off_bufB + node_elems * sizeof(float);      // 153.6 MB
    const size_t off_start   = off_packed + (size_t)N_EDGES * sizeof(Edge);// 193.6 MB
    const size_t off_bcursor = off_start + (N_NODES + 4) * sizeof(int);
    const size_t needed      = off_bcursor + (NBUCK + 4) * sizeof(int);    // ~195 MB

    const int nt4       = N_NODES * EMB / 4;
    const int el_blocks = (nt4 + 255) / 256;                 // 18750
    const int e_blocks  = (N_EDGES + 255) / 256;

    // stage capacity check: NBUCK * CAP * 8 B = 48.2 MB <= bufB region (76.8 MB)
    static_assert((size_t)NBUCK * CAP * sizeof(SRec) <= (size_t)N_NODES * EMB * sizeof(float),
                  "stage must fit in bufB");

    if (ws_size >= needed) {
        // ---- CSR path (fp16 tables) ----
        f16*  bufA    = (f16*) (ws + off_bufA);
        f16*  bufB    = (f16*) (ws + off_bufB);
        Edge* packed  = (Edge*)(ws + off_packed);
        int*  start   = (int*) (ws + off_start);
        int*  bcursor = (int*) (ws + off_bcursor);
        SRec* stage   = (SRec*)(ws + off_bufB);

        hipMemsetAsync(bcursor, 0, (NBUCK + 4) * sizeof(int), stream);

        const int bin_blocks = (N_EDGES + BIN_CHUNK - 1) / BIN_CHUNK;      // 306
        fused_init_bin_kernel<<<bin_blocks + el_blocks, 256, 0, stream>>>(
            emb_user, emb_item, bufA, out,
            (const int4*)edge_row, (const int4*)edge_col, (const float4*)edge_val,
            bcursor, stage, bin_blocks);

        bucket_scan_scatter_kernel<<<NBUCK, 1024, 0, stream>>>(
            stage, bcursor, start, packed);

        const int row_blocks = (N_NODES + 15) / 16;
        f16* cur = bufA;
        f16* nxt = bufB;
        for (int layer = 0; layer < 3; ++layer) {
            spmm_csr_kernel<<<row_blocks, 256, 0, stream>>>(
                cur, packed, start, nxt, out,
                (layer == 2) ? 0.25f : 1.0f,
                (layer == 2) ? 0 : 1);
            f16* tmp = cur; cur = nxt; nxt = tmp;
        }
    } else {
        // ---- fallback: fp32 atomic path (needs only 153.6 MB) ----
        float* fbufA = (float*)(ws + off_bufA);
        float* fbufB = (float*)(ws + off_bufB);
        init_kernel<<<el_blocks, 256, 0, stream>>>(emb_user, emb_item, fbufA, out);
        const int ew_blocks = (N_EDGES * 16 + 255) / 256;
        float* cur = fbufA;
        float* nxt = fbufB;
        for (int layer = 0; layer < 3; ++layer) {
            hipMemsetAsync(nxt, 0, node_elems * sizeof(float), stream);
            spmm_atomic_kernel<<<ew_blocks, 256, 0, stream>>>(
                cur, edge_val, edge_row, edge_col, nxt);
            addscale_kernel<<<el_blocks, 256, 0, stream>>>(
                nxt, out, (layer == 2) ? 0.25f : 1.0f);
            float* tmp = cur; cur = nxt; nxt = tmp;
        }
    }
}

// Round 7
// 651.578 us; speedup vs baseline: 1.8111x; 1.0067x over previous
//
#include <hip/hip_runtime.h>

#define N_USERS 200000
#define N_ITEMS 100000
#define N_NODES 300000
#define EMB     64
#define N_EDGES 5000000

typedef float f32x4 __attribute__((ext_vector_type(4)));
typedef _Float16 f16;
typedef f16 f16x4 __attribute__((ext_vector_type(4)));     // 8 B gather granule

// 8 B staged record: rc = (rowLow10 << 19) | col  (col < 2^19)
struct alignas(8) SRec { unsigned int rc; float val; };

#define BSHIFT 10
#define BROWS  (1 << BSHIFT)                               // 1024
#define NBUCK  ((N_NODES + BROWS - 1) >> BSHIFT)           // 293
#define CAP    20480                                       // mean 17065 (+26 sigma)
#define BIN_CHUNK 16384                                    // edges per bin block (2-pass)
#define COLMASK 0x7FFFFu

// ---------------------------------------------------------------------------
// Fused init + bin.
//  blocks [0, bin_blocks)          : TWO-PASS bin of 16384 edges/block
//    (runs ~56 edges = 446 B per bucket claim -> line-dense)
//  blocks [bin_blocks, +el_blocks) : x0 = fp16(cat(user,item))
//  NOTE: out is NOT written here anymore (deferred combine writes it once,
//  in the layer-2 spmm epilogue) -> saves a 76.8 MB stream.
// ---------------------------------------------------------------------------
__global__ __launch_bounds__(256) void fused_init_bin_kernel(
    const float* __restrict__ user, const float* __restrict__ item,
    f16* __restrict__ x0,
    const int4* __restrict__ row4, const int4* __restrict__ col4,
    const float4* __restrict__ val4,
    int* __restrict__ bcursor, SRec* __restrict__ stage, int bin_blocks)
{
    int t = threadIdx.x;
    if ((int)blockIdx.x < bin_blocks) {
        __shared__ int hist[NBUCK];
        __shared__ int base_[NBUCK];
        const int Q = N_EDGES / 4;                    // int4 count (N_EDGES%4==0)
        long q0 = (long)blockIdx.x * (BIN_CHUNK / 4); // 4096 int4 / block

        for (int k = t; k < NBUCK; k += 256) hist[k] = 0;
        __syncthreads();

        // pass A: count 16K edges
        #pragma unroll
        for (int k = 0; k < 16; ++k) {
            long q = q0 + k * 256 + t;
            if (q < Q) {
                int4 r = row4[q];
                atomicAdd(&hist[r.x >> BSHIFT], 1);
                atomicAdd(&hist[r.y >> BSHIFT], 1);
                atomicAdd(&hist[r.z >> BSHIFT], 1);
                atomicAdd(&hist[r.w >> BSHIFT], 1);
            }
        }
        __syncthreads();
        // one claim per bucket for the whole 16K chunk -> dense runs
        for (int k = t; k < NBUCK; k += 256) {
            int h = hist[k];
            base_[k] = h ? atomicAdd(&bcursor[k], h) : 0;
            hist[k] = 0;                               // reuse as local cursor
        }
        __syncthreads();
        // pass B: re-read (rows L2-warm) and scatter
        #pragma unroll
        for (int k = 0; k < 16; ++k) {
            long q = q0 + k * 256 + t;
            if (q < Q) {
                int4 r = row4[q]; int4 c = col4[q]; float4 v = val4[q];
                int   rr[4] = {r.x, r.y, r.z, r.w};
                int   cc[4] = {c.x, c.y, c.z, c.w};
                float vv[4] = {v.x, v.y, v.z, v.w};
                #pragma unroll
                for (int j = 0; j < 4; ++j) {
                    int b   = rr[j] >> BSHIFT;
                    int pos = base_[b] + atomicAdd(&hist[b], 1);
                    SRec s;
                    s.rc  = ((unsigned)(rr[j] & (BROWS - 1)) << 19) | (unsigned)cc[j];
                    s.val = vv[j];
                    stage[(size_t)b * CAP + pos] = s;
                }
            }
        }
    } else {
        const int nu4 = N_USERS * EMB / 4;
        const int nt4 = N_NODES * EMB / 4;
        int i = ((int)blockIdx.x - bin_blocks) * 256 + t;
        if (i >= nt4) return;
        float4 vv = (i < nu4) ? reinterpret_cast<const float4*>(user)[i]
                              : reinterpret_cast<const float4*>(item)[i - nu4];
        f16x4 hx = {(f16)vv.x, (f16)vv.y, (f16)vv.z, (f16)vv.w};
        reinterpret_cast<f16x4*>(x0)[i] = hx;
    }
}

// ---------------------------------------------------------------------------
// Per-bucket: count rows in LDS -> LDS scan -> bucket base (prefix over 293
// sizes) -> write start[] -> scatter to SoA packed (cols int32, vals f16).
// 293 blocks (was 147: 57% CU coverage was the bottleneck of this kernel).
// ---------------------------------------------------------------------------
__global__ __launch_bounds__(1024) void bucket_scan_scatter_kernel(
    const SRec* __restrict__ stage, const int* __restrict__ bsize,
    int* __restrict__ start, int* __restrict__ pcol, f16* __restrict__ pval)
{
    __shared__ int sizes[NBUCK];
    __shared__ int cur[BROWS];
    __shared__ int sc[1024];
    __shared__ int sbase;

    int b    = blockIdx.x;
    int t    = threadIdx.x;
    int row0 = b << BSHIFT;
    int rows = N_NODES - row0; if (rows > BROWS) rows = BROWS;

    if (t < NBUCK) sizes[t] = bsize[t];
    cur[t] = 0;                         // reuse as per-row count first
    __syncthreads();
    if (t == 0) {                       // bucket base: serial prefix over LDS
        int s = 0;
        for (int k = 0; k < b; ++k) s += sizes[k];
        sbase = s;
    }
    __syncthreads();
    const int  base = sbase;
    const int  size = sizes[b];
    const SRec* seg = stage + (size_t)b * CAP;

    // pass A: per-row counts
    for (int e = t; e < size; e += 1024)
        atomicAdd(&cur[seg[e].rc >> 19], 1);
    __syncthreads();

    // exclusive scan over 1024 counts (one per thread, Hillis-Steele)
    int a = cur[t];
    sc[t] = a;
    __syncthreads();
    for (int ofs = 1; ofs < 1024; ofs <<= 1) {
        int v = (t >= ofs) ? sc[t - ofs] : 0;
        __syncthreads();
        sc[t] += v;
        __syncthreads();
    }
    cur[t] = base + sc[t] - a;          // exclusive + bucket base
    __syncthreads();

    if (t < rows) start[row0 + t] = cur[t];
    if (b == NBUCK - 1 && t == 0) start[N_NODES] = N_EDGES;
    __syncthreads();

    // pass B: scatter (seg is L2-warm from pass A)
    for (int e = t; e < size; e += 1024) {
        SRec srec = seg[e];
        int pos = atomicAdd(&cur[srec.rc >> 19], 1);
        pcol[pos] = (int)(srec.rc & COLMASK);
        pval[pos] = (f16)srec.val;
    }
}

// ---------------------------------------------------------------------------
// CSR SpMM over fp16 tables. mode 0: write y only (layers 0,1 -- out is
// untouched). mode 1 (layer 2): epilogue out = 0.25*(x0 + x1 + x2 + acc),
// write-only out (x2 == the gather table x, row-sequential read).
// Established (R1/R2/R5/R6): miss-path-byte-bound at ~3.87 TB/s; dur tracks
// bytes exactly. This round removes the out RMW stream from layers 0/1.
// ---------------------------------------------------------------------------
__global__ __launch_bounds__(256, 4) void spmm_csr_kernel(
    const f16* __restrict__ x, const int* __restrict__ pcol,
    const f16* __restrict__ pval, const int* __restrict__ start,
    f16* __restrict__ y,
    const f16* __restrict__ xa, const f16* __restrict__ xb,
    float* __restrict__ out, int mode)
{
    int g = blockIdx.x * (256 / 16) + (threadIdx.x >> 4);
    if (g >= N_NODES) return;
    const int lane16 = threadIdx.x & 15;
    const int d      = lane16 * 4;
    const int gbase  = threadIdx.x & 48;

    int beg = start[g];
    int end = start[g + 1];
    float4 acc = {0.f, 0.f, 0.f, 0.f};

    for (int jb = beg; jb < end; jb += 16) {
        int   mycol = 0; float myval = 0.f;
        if (jb + lane16 < end) {
            mycol = pcol[jb + lane16];
            myval = (float)pval[jb + lane16];
        }

        int   cols[16];
        float vals[16];
        #pragma unroll
        for (int k = 0; k < 16; ++k) {
            cols[k] = __shfl(mycol, gbase + k, 64);
            vals[k] = __shfl(myval, gbase + k, 64);
        }

        f16x4 xv[16];
        #pragma unroll
        for (int k = 0; k < 16; ++k) {
            xv[k] = *reinterpret_cast<const f16x4*>(
                x + (size_t)cols[k] * EMB + d);
        }

        #pragma unroll
        for (int k = 0; k < 16; ++k) {
            acc.x += vals[k] * (float)xv[k].x;
            acc.y += vals[k] * (float)xv[k].y;
            acc.z += vals[k] * (float)xv[k].z;
            acc.w += vals[k] * (float)xv[k].w;
        }
    }

    const size_t rofs = (size_t)g * EMB + d;
    if (mode == 0) {
        f16x4 hy = {(f16)acc.x, (f16)acc.y, (f16)acc.z, (f16)acc.w};
        *reinterpret_cast<f16x4*>(y + rofs) = hy;
    } else {
        f16x4 v0 = *reinterpret_cast<const f16x4*>(xa + rofs);
        f16x4 v1 = *reinterpret_cast<const f16x4*>(xb + rofs);
        f16x4 v2 = *reinterpret_cast<const f16x4*>(x  + rofs);
        f32x4 o;
        o.x = 0.25f * ((float)v0.x + (float)v1.x + (float)v2.x + acc.x);
        o.y = 0.25f * ((float)v0.y + (float)v1.y + (float)v2.y + acc.y);
        o.z = 0.25f * ((float)v0.z + (float)v1.z + (float)v2.z + acc.z);
        o.w = 0.25f * ((float)v0.w + (float)v1.w + (float)v2.w + acc.w);
        __builtin_nontemporal_store(o, reinterpret_cast<f32x4*>(out + rofs));
    }
}

// ---------------------------------------------------------------------------
// Fallback path (ws too small for CSR): unchanged fp32 atomic path.
// ---------------------------------------------------------------------------
__global__ __launch_bounds__(256) void init_kernel(
    const float* __restrict__ user, const float* __restrict__ item,
    float* __restrict__ x, float* __restrict__ out)
{
    const int nu4 = N_USERS * EMB / 4;
    const int nt4 = N_NODES * EMB / 4;
    int i = blockIdx.x * blockDim.x + threadIdx.x;
    if (i >= nt4) return;
    float4 v = (i < nu4) ? reinterpret_cast<const float4*>(user)[i]
                         : reinterpret_cast<const float4*>(item)[i - nu4];
    reinterpret_cast<float4*>(x)[i]   = v;
    reinterpret_cast<float4*>(out)[i] = v;
}

__global__ __launch_bounds__(256) void spmm_atomic_kernel(
    const float* __restrict__ x, const float* __restrict__ val,
    const int* __restrict__ row, const int* __restrict__ col,
    float* __restrict__ y)
{
    int t = blockIdx.x * blockDim.x + threadIdx.x;
    int e = t >> 4;
    if (e >= N_EDGES) return;
    int d = (t & 15) * 4;
    int   r = row[e];
    int   c = col[e];
    float v = val[e];
    float4 xv = *reinterpret_cast<const float4*>(x + c * EMB + d);
    float* yp = y + r * EMB + d;
    unsafeAtomicAdd(yp + 0, v * xv.x);
    unsafeAtomicAdd(yp + 1, v * xv.y);
    unsafeAtomicAdd(yp + 2, v * xv.z);
    unsafeAtomicAdd(yp + 3, v * xv.w);
}

__global__ __launch_bounds__(256) void addscale_kernel(
    const float* __restrict__ xl, float* __restrict__ out, float scale)
{
    const int nt4 = N_NODES * EMB / 4;
    int i = blockIdx.x * blockDim.x + threadIdx.x;
    if (i >= nt4) return;
    float4 a = reinterpret_cast<float4*>(out)[i];
    float4 b = reinterpret_cast<const float4*>(xl)[i];
    a.x = (a.x + b.x) * scale;
    a.y = (a.y + b.y) * scale;
    a.z = (a.z + b.z) * scale;
    a.w = (a.w + b.w) * scale;
    reinterpret_cast<float4*>(out)[i] = a;
}

extern "C" void kernel_launch(void* const* d_in, const int* in_sizes, int n_in,
                              void* d_out, int out_size, void* d_ws, size_t ws_size,
                              hipStream_t stream) {
    const float* emb_user = (const float*)d_in[0];
    const float* emb_item = (const float*)d_in[1];
    const float* edge_val = (const float*)d_in[2];
    const int*   edge_row = (const int*)d_in[3];
    const int*   edge_col = (const int*)d_in[4];
    float* out = (float*)d_out;

    const size_t node_elems = (size_t)N_NODES * EMB;        // 19.2M elems
    char* ws = (char*)d_ws;

    // workspace layout (regions sized fp32-era for compat with ws checks):
    //  region A (76.8 MB): x0 fp16 [0,38.4) | x2 fp16 [38.4,76.8)
    //  region B (76.8 MB): stage 48.2 MB during build; x1 fp16 [0,38.4) after
    //  packed SoA: cols 20 MB + vals 10 MB
    const size_t off_bufA    = 0;
    const size_t off_bufB    = off_bufA + node_elems * sizeof(float);      // 76.8 MB
    const size_t off_pcol    = off_bufB + node_elems * sizeof(float);      // 153.6 MB
    const size_t off_pval    = off_pcol + (size_t)N_EDGES * sizeof(int);   // 173.6 MB
    const size_t off_start   = off_pval + (size_t)N_EDGES * sizeof(f16);   // 183.6 MB
    const size_t off_bcursor = off_start + (N_NODES + 4) * sizeof(int);
    const size_t needed      = off_bcursor + (NBUCK + 4) * sizeof(int);    // ~185 MB

    const int nt4       = N_NODES * EMB / 4;
    const int el_blocks = (nt4 + 255) / 256;                 // 18750
    const int e_blocks  = (N_EDGES + 255) / 256;

    // stage capacity check: NBUCK * CAP * 8 B = 48.0 MB <= region B (76.8 MB)
    static_assert((size_t)NBUCK * CAP * sizeof(SRec) <= (size_t)N_NODES * EMB * sizeof(float),
                  "stage must fit in bufB region");

    if (ws_size >= needed) {
        // ---- CSR path (fp16 tables, SoA packed, deferred combine) ----
        f16*  x0buf   = (f16*) (ws + off_bufA);
        f16*  x2buf   = (f16*) (ws + off_bufA) + node_elems;   // +38.4 MB
        f16*  x1buf   = (f16*) (ws + off_bufB);
        int*  pcol    = (int*) (ws + off_pcol);
        f16*  pval    = (f16*) (ws + off_pval);
        int*  start   = (int*) (ws + off_start);
        int*  bcursor = (int*) (ws + off_bcursor);
        SRec* stage   = (SRec*)(ws + off_bufB);   // dead after scatter; x1 reuses

        hipMemsetAsync(bcursor, 0, (NBUCK + 4) * sizeof(int), stream);

        const int bin_blocks = (N_EDGES + BIN_CHUNK - 1) / BIN_CHUNK;      // 306
        fused_init_bin_kernel<<<bin_blocks + el_blocks, 256, 0, stream>>>(
            emb_user, emb_item, x0buf,
            (const int4*)edge_row, (const int4*)edge_col, (const float4*)edge_val,
            bcursor, stage, bin_blocks);

        bucket_scan_scatter_kernel<<<NBUCK, 1024, 0, stream>>>(
            stage, bcursor, start, pcol, pval);

        const int row_blocks = (N_NODES + 15) / 16;
        // L0: x0 -> x1   (x1 overwrites stage: stage is dead after scatter)
        spmm_csr_kernel<<<row_blocks, 256, 0, stream>>>(
            x0buf, pcol, pval, start, x1buf, nullptr, nullptr, nullptr, 0);
        // L1: x1 -> x2
        spmm_csr_kernel<<<row_blocks, 256, 0, stream>>>(
            x1buf, pcol, pval, start, x2buf, nullptr, nullptr, nullptr, 0);
        // L2: x2 -> epilogue: out = 0.25*(x0+x1+x2+acc), write-only out
        spmm_csr_kernel<<<row_blocks, 256, 0, stream>>>(
            x2buf, pcol, pval, start, nullptr, x0buf, x1buf, out, 1);
    } else {
        // ---- fallback: fp32 atomic path (needs only 153.6 MB) ----
        float* fbufA = (float*)(ws + off_bufA);
        float* fbufB = (float*)(ws + off_bufB);
        init_kernel<<<el_blocks, 256, 0, stream>>>(emb_user, emb_item, fbufA, out);
        const int ew_blocks = (N_EDGES * 16 + 255) / 256;
        float* cur = fbufA;
        float* nxt = fbufB;
        for (int layer = 0; layer < 3; ++layer) {
            hipMemsetAsync(nxt, 0, node_elems * sizeof(float), stream);
            spmm_atomic_kernel<<<ew_blocks, 256, 0, stream>>>(
                cur, edge_val, edge_row, edge_col, nxt);
            addscale_kernel<<<el_blocks, 256, 0, stream>>>(
                nxt, out, (layer == 2) ? 0.25f : 1.0f);
            float* tmp = cur; cur = nxt; nxt = tmp;
        }
    }
}

// Round 8
// 632.238 us; speedup vs baseline: 1.8665x; 1.0306x over previous
//
#include <hip/hip_runtime.h>

#define N_USERS 200000
#define N_ITEMS 100000
#define N_NODES 300000
#define EMB     64
#define N_EDGES 5000000

typedef float f32x4 __attribute__((ext_vector_type(4)));
typedef _Float16 f16;
typedef f16 f16x4 __attribute__((ext_vector_type(4)));     // 8 B gather granule

// 8 B staged record: rc = (rowLow10 << 19) | col  (col < 2^19)
struct alignas(8) SRec { unsigned int rc; float val; };

#define BSHIFT 10
#define BROWS  (1 << BSHIFT)                               // 1024
#define NBUCK  ((N_NODES + BROWS - 1) >> BSHIFT)           // 293
#define CAP    20480                                       // mean 17065 (+26 sigma)
#define BIN_CHUNK 16384                                    // edges per bin block (2-pass)
#define COLMASK 0x7FFFFu
#define INIT_BLOCKS 2048                                   // grid-strided init part

// ---------------------------------------------------------------------------
// Fused init + bin.
//  blocks [0, bin_blocks)            : TWO-PASS bin of 16384 edges/block.
//    R7 PMC showed VGPR=28, Occ 37%, VALU 3%, 1.56 TB/s -> latency-bound,
//    one VMEM round trip exposed per edge-quad. This round:
//      pass A: batch-load ra[16] (16 loads in flight), then count
//      pass B: REUSE ra (row re-read eliminated), col/val batched x4
//  blocks [bin_blocks, +INIT_BLOCKS) : grid-strided x0 = fp16(cat(user,item))
//    (was 18750 one-shot blocks = dispatch churn + zero ILP)
// ---------------------------------------------------------------------------
__global__ __launch_bounds__(256) void fused_init_bin_kernel(
    const float* __restrict__ user, const float* __restrict__ item,
    f16* __restrict__ x0,
    const int4* __restrict__ row4, const int4* __restrict__ col4,
    const float4* __restrict__ val4,
    int* __restrict__ bcursor, SRec* __restrict__ stage, int bin_blocks)
{
    int t = threadIdx.x;
    if ((int)blockIdx.x < bin_blocks) {
        __shared__ int hist[NBUCK];
        __shared__ int base_[NBUCK];
        const int Q = N_EDGES / 4;                    // int4 count (N_EDGES%4==0)
        long q0 = (long)blockIdx.x * (BIN_CHUNK / 4); // 4096 int4 / block

        for (int k = t; k < NBUCK; k += 256) hist[k] = 0;
        __syncthreads();

        // ---- pass A: batch row loads, then count 16K edges ----
        int4 ra[16];
        const bool full = (q0 + (BIN_CHUNK / 4) <= Q);
        if (full) {
            #pragma unroll
            for (int k = 0; k < 16; ++k)
                ra[k] = row4[q0 + k * 256 + t];
            #pragma unroll
            for (int k = 0; k < 16; ++k) {
                atomicAdd(&hist[ra[k].x >> BSHIFT], 1);
                atomicAdd(&hist[ra[k].y >> BSHIFT], 1);
                atomicAdd(&hist[ra[k].z >> BSHIFT], 1);
                atomicAdd(&hist[ra[k].w >> BSHIFT], 1);
            }
        } else {
            #pragma unroll
            for (int k = 0; k < 16; ++k) {
                long q = q0 + k * 256 + t;
                if (q < Q) {
                    ra[k] = row4[q];
                    atomicAdd(&hist[ra[k].x >> BSHIFT], 1);
                    atomicAdd(&hist[ra[k].y >> BSHIFT], 1);
                    atomicAdd(&hist[ra[k].z >> BSHIFT], 1);
                    atomicAdd(&hist[ra[k].w >> BSHIFT], 1);
                }
            }
        }
        __syncthreads();
        // one claim per bucket for the whole 16K chunk -> dense runs
        for (int k = t; k < NBUCK; k += 256) {
            int h = hist[k];
            base_[k] = h ? atomicAdd(&bcursor[k], h) : 0;
            hist[k] = 0;                               // reuse as local cursor
        }
        __syncthreads();
        // ---- pass B: col/val batched x4, rows from registers ----
        #pragma unroll
        for (int g = 0; g < 4; ++g) {
            int4 c4[4]; float4 v4[4];
            #pragma unroll
            for (int j = 0; j < 4; ++j) {
                long q = q0 + (g * 4 + j) * 256 + t;
                if (q < Q) { c4[j] = col4[q]; v4[j] = val4[q]; }
            }
            #pragma unroll
            for (int j = 0; j < 4; ++j) {
                long q = q0 + (g * 4 + j) * 256 + t;
                if (q < Q) {
                    int4 r = ra[g * 4 + j];
                    int   rr[4] = {r.x, r.y, r.z, r.w};
                    int   cc[4] = {c4[j].x, c4[j].y, c4[j].z, c4[j].w};
                    float vv[4] = {v4[j].x, v4[j].y, v4[j].z, v4[j].w};
                    #pragma unroll
                    for (int m = 0; m < 4; ++m) {
                        int b   = rr[m] >> BSHIFT;
                        int pos = base_[b] + atomicAdd(&hist[b], 1);
                        SRec s;
                        s.rc  = ((unsigned)(rr[m] & (BROWS - 1)) << 19)
                              | (unsigned)cc[m];
                        s.val = vv[m];
                        stage[(size_t)b * CAP + pos] = s;
                    }
                }
            }
        }
    } else {
        const int nu4 = N_USERS * EMB / 4;
        const int nt4 = N_NODES * EMB / 4;
        int i0 = ((int)blockIdx.x - bin_blocks) * 256 + t;
        const int stride = INIT_BLOCKS * 256;
        for (int i = i0; i < nt4; i += stride) {
            float4 vv = (i < nu4) ? reinterpret_cast<const float4*>(user)[i]
                                  : reinterpret_cast<const float4*>(item)[i - nu4];
            f16x4 hx = {(f16)vv.x, (f16)vv.y, (f16)vv.z, (f16)vv.w};
            reinterpret_cast<f16x4*>(x0)[i] = hx;
        }
    }
}

// ---------------------------------------------------------------------------
// Per-bucket: count rows in LDS -> LDS scan -> bucket base (prefix over 293
// sizes) -> write start[] -> scatter to SoA packed (cols int32, vals f16).
// ---------------------------------------------------------------------------
__global__ __launch_bounds__(1024) void bucket_scan_scatter_kernel(
    const SRec* __restrict__ stage, const int* __restrict__ bsize,
    int* __restrict__ start, int* __restrict__ pcol, f16* __restrict__ pval)
{
    __shared__ int sizes[NBUCK];
    __shared__ int cur[BROWS];
    __shared__ int sc[1024];
    __shared__ int sbase;

    int b    = blockIdx.x;
    int t    = threadIdx.x;
    int row0 = b << BSHIFT;
    int rows = N_NODES - row0; if (rows > BROWS) rows = BROWS;

    if (t < NBUCK) sizes[t] = bsize[t];
    cur[t] = 0;                         // reuse as per-row count first
    __syncthreads();
    if (t == 0) {                       // bucket base: serial prefix over LDS
        int s = 0;
        for (int k = 0; k < b; ++k) s += sizes[k];
        sbase = s;
    }
    __syncthreads();
    const int  base = sbase;
    const int  size = sizes[b];
    const SRec* seg = stage + (size_t)b * CAP;

    // pass A: per-row counts
    for (int e = t; e < size; e += 1024)
        atomicAdd(&cur[seg[e].rc >> 19], 1);
    __syncthreads();

    // exclusive scan over 1024 counts (one per thread, Hillis-Steele)
    int a = cur[t];
    sc[t] = a;
    __syncthreads();
    for (int ofs = 1; ofs < 1024; ofs <<= 1) {
        int v = (t >= ofs) ? sc[t - ofs] : 0;
        __syncthreads();
        sc[t] += v;
        __syncthreads();
    }
    cur[t] = base + sc[t] - a;          // exclusive + bucket base
    __syncthreads();

    if (t < rows) start[row0 + t] = cur[t];
    if (b == NBUCK - 1 && t == 0) start[N_NODES] = N_EDGES;
    __syncthreads();

    // pass B: scatter (seg is L2-warm from pass A)
    for (int e = t; e < size; e += 1024) {
        SRec srec = seg[e];
        int pos = atomicAdd(&cur[srec.rc >> 19], 1);
        pcol[pos] = (int)(srec.rc & COLMASK);
        pval[pos] = (f16)srec.val;
    }
}

// ---------------------------------------------------------------------------
// CSR SpMM over fp16 tables. mode 0: write y only (layers 0,1). mode 1
// (layer 2): epilogue out = 0.25*(x0 + x1 + x2 + acc), write-only out.
// Established: miss-path-byte-bound at ~3.87 TB/s; dur tracks bytes exactly.
// ---------------------------------------------------------------------------
__global__ __launch_bounds__(256, 4) void spmm_csr_kernel(
    const f16* __restrict__ x, const int* __restrict__ pcol,
    const f16* __restrict__ pval, const int* __restrict__ start,
    f16* __restrict__ y,
    const f16* __restrict__ xa, const f16* __restrict__ xb,
    float* __restrict__ out, int mode)
{
    int g = blockIdx.x * (256 / 16) + (threadIdx.x >> 4);
    if (g >= N_NODES) return;
    const int lane16 = threadIdx.x & 15;
    const int d      = lane16 * 4;
    const int gbase  = threadIdx.x & 48;

    int beg = start[g];
    int end = start[g + 1];
    float4 acc = {0.f, 0.f, 0.f, 0.f};

    for (int jb = beg; jb < end; jb += 16) {
        int   mycol = 0; float myval = 0.f;
        if (jb + lane16 < end) {
            mycol = pcol[jb + lane16];
            myval = (float)pval[jb + lane16];
        }

        int   cols[16];
        float vals[16];
        #pragma unroll
        for (int k = 0; k < 16; ++k) {
            cols[k] = __shfl(mycol, gbase + k, 64);
            vals[k] = __shfl(myval, gbase + k, 64);
        }

        f16x4 xv[16];
        #pragma unroll
        for (int k = 0; k < 16; ++k) {
            xv[k] = *reinterpret_cast<const f16x4*>(
                x + (size_t)cols[k] * EMB + d);
        }

        #pragma unroll
        for (int k = 0; k < 16; ++k) {
            acc.x += vals[k] * (float)xv[k].x;
            acc.y += vals[k] * (float)xv[k].y;
            acc.z += vals[k] * (float)xv[k].z;
            acc.w += vals[k] * (float)xv[k].w;
        }
    }

    const size_t rofs = (size_t)g * EMB + d;
    if (mode == 0) {
        f16x4 hy = {(f16)acc.x, (f16)acc.y, (f16)acc.z, (f16)acc.w};
        *reinterpret_cast<f16x4*>(y + rofs) = hy;
    } else {
        f16x4 v0 = *reinterpret_cast<const f16x4*>(xa + rofs);
        f16x4 v1 = *reinterpret_cast<const f16x4*>(xb + rofs);
        f16x4 v2 = *reinterpret_cast<const f16x4*>(x  + rofs);
        f32x4 o;
        o.x = 0.25f * ((float)v0.x + (float)v1.x + (float)v2.x + acc.x);
        o.y = 0.25f * ((float)v0.y + (float)v1.y + (float)v2.y + acc.y);
        o.z = 0.25f * ((float)v0.z + (float)v1.z + (float)v2.z + acc.z);
        o.w = 0.25f * ((float)v0.w + (float)v1.w + (float)v2.w + acc.w);
        __builtin_nontemporal_store(o, reinterpret_cast<f32x4*>(out + rofs));
    }
}

// ---------------------------------------------------------------------------
// Fallback path (ws too small for CSR): unchanged fp32 atomic path.
// ---------------------------------------------------------------------------
__global__ __launch_bounds__(256) void init_kernel(
    const float* __restrict__ user, const float* __restrict__ item,
    float* __restrict__ x, float* __restrict__ out)
{
    const int nu4 = N_USERS * EMB / 4;
    const int nt4 = N_NODES * EMB / 4;
    int i = blockIdx.x * blockDim.x + threadIdx.x;
    if (i >= nt4) return;
    float4 v = (i < nu4) ? reinterpret_cast<const float4*>(user)[i]
                         : reinterpret_cast<const float4*>(item)[i - nu4];
    reinterpret_cast<float4*>(x)[i]   = v;
    reinterpret_cast<float4*>(out)[i] = v;
}

__global__ __launch_bounds__(256) void spmm_atomic_kernel(
    const float* __restrict__ x, const float* __restrict__ val,
    const int* __restrict__ row, const int* __restrict__ col,
    float* __restrict__ y)
{
    int t = blockIdx.x * blockDim.x + threadIdx.x;
    int e = t >> 4;
    if (e >= N_EDGES) return;
    int d = (t & 15) * 4;
    int   r = row[e];
    int   c = col[e];
    float v = val[e];
    float4 xv = *reinterpret_cast<const float4*>(x + c * EMB + d);
    float* yp = y + r * EMB + d;
    unsafeAtomicAdd(yp + 0, v * xv.x);
    unsafeAtomicAdd(yp + 1, v * xv.y);
    unsafeAtomicAdd(yp + 2, v * xv.z);
    unsafeAtomicAdd(yp + 3, v * xv.w);
}

__global__ __launch_bounds__(256) void addscale_kernel(
    const float* __restrict__ xl, float* __restrict__ out, float scale)
{
    const int nt4 = N_NODES * EMB / 4;
    int i = blockIdx.x * blockDim.x + threadIdx.x;
    if (i >= nt4) return;
    float4 a = reinterpret_cast<float4*>(out)[i];
    float4 b = reinterpret_cast<const float4*>(xl)[i];
    a.x = (a.x + b.x) * scale;
    a.y = (a.y + b.y) * scale;
    a.z = (a.z + b.z) * scale;
    a.w = (a.w + b.w) * scale;
    reinterpret_cast<float4*>(out)[i] = a;
}

extern "C" void kernel_launch(void* const* d_in, const int* in_sizes, int n_in,
                              void* d_out, int out_size, void* d_ws, size_t ws_size,
                              hipStream_t stream) {
    const float* emb_user = (const float*)d_in[0];
    const float* emb_item = (const float*)d_in[1];
    const float* edge_val = (const float*)d_in[2];
    const int*   edge_row = (const int*)d_in[3];
    const int*   edge_col = (const int*)d_in[4];
    float* out = (float*)d_out;

    const size_t node_elems = (size_t)N_NODES * EMB;        // 19.2M elems
    char* ws = (char*)d_ws;

    // workspace layout:
    //  region A (76.8 MB): x0 fp16 [0,38.4) | x2 fp16 [38.4,76.8)
    //  region B (76.8 MB): stage 48 MB during build; x1 fp16 [0,38.4) after
    //  packed SoA: cols 20 MB + vals 10 MB
    const size_t off_bufA    = 0;
    const size_t off_bufB    = off_bufA + node_elems * sizeof(float);      // 76.8 MB
    const size_t off_pcol    = off_bufB + node_elems * sizeof(float);      // 153.6 MB
    const size_t off_pval    = off_pcol + (size_t)N_EDGES * sizeof(int);   // 173.6 MB
    const size_t off_start   = off_pval + (size_t)N_EDGES * sizeof(f16);   // 183.6 MB
    const size_t off_bcursor = off_start + (N_NODES + 4) * sizeof(int);
    const size_t needed      = off_bcursor + (NBUCK + 4) * sizeof(int);    // ~185 MB

    const int nt4       = N_NODES * EMB / 4;
    const int el_blocks = (nt4 + 255) / 256;
    const int e_blocks  = (N_EDGES + 255) / 256;

    static_assert((size_t)NBUCK * CAP * sizeof(SRec) <= (size_t)N_NODES * EMB * sizeof(float),
                  "stage must fit in bufB region");

    if (ws_size >= needed) {
        // ---- CSR path (fp16 tables, SoA packed, deferred combine) ----
        f16*  x0buf   = (f16*) (ws + off_bufA);
        f16*  x2buf   = (f16*) (ws + off_bufA) + node_elems;   // +38.4 MB
        f16*  x1buf   = (f16*) (ws + off_bufB);
        int*  pcol    = (int*) (ws + off_pcol);
        f16*  pval    = (f16*) (ws + off_pval);
        int*  start   = (int*) (ws + off_start);
        int*  bcursor = (int*) (ws + off_bcursor);
        SRec* stage   = (SRec*)(ws + off_bufB);   // dead after scatter; x1 reuses

        hipMemsetAsync(bcursor, 0, (NBUCK + 4) * sizeof(int), stream);

        const int bin_blocks = (N_EDGES + BIN_CHUNK - 1) / BIN_CHUNK;      // 306
        fused_init_bin_kernel<<<bin_blocks + INIT_BLOCKS, 256, 0, stream>>>(
            emb_user, emb_item, x0buf,
            (const int4*)edge_row, (const int4*)edge_col, (const float4*)edge_val,
            bcursor, stage, bin_blocks);

        bucket_scan_scatter_kernel<<<NBUCK, 1024, 0, stream>>>(
            stage, bcursor, start, pcol, pval);

        const int row_blocks = (N_NODES + 15) / 16;
        // L0: x0 -> x1   (x1 overwrites stage: stage is dead after scatter)
        spmm_csr_kernel<<<row_blocks, 256, 0, stream>>>(
            x0buf, pcol, pval, start, x1buf, nullptr, nullptr, nullptr, 0);
        // L1: x1 -> x2
        spmm_csr_kernel<<<row_blocks, 256, 0, stream>>>(
            x1buf, pcol, pval, start, x2buf, nullptr, nullptr, nullptr, 0);
        // L2: x2 -> epilogue: out = 0.25*(x0+x1+x2+acc), write-only out
        spmm_csr_kernel<<<row_blocks, 256, 0, stream>>>(
            x2buf, pcol, pval, start, nullptr, x0buf, x1buf, out, 1);
    } else {
        // ---- fallback: fp32 atomic path (needs only 153.6 MB) ----
        float* fbufA = (float*)(ws + off_bufA);
        float* fbufB = (float*)(ws + off_bufB);
        init_kernel<<<el_blocks, 256, 0, stream>>>(emb_user, emb_item, fbufA, out);
        const int ew_blocks = (N_EDGES * 16 + 255) / 256;
        float* cur = fbufA;
        float* nxt = fbufB;
        for (int layer = 0; layer < 3; ++layer) {
            hipMemsetAsync(nxt, 0, node_elems * sizeof(float), stream);
            spmm_atomic_kernel<<<ew_blocks, 256, 0, stream>>>(
                cur, edge_val, edge_row, edge_col, nxt);
            addscale_kernel<<<el_blocks, 256, 0, stream>>>(
                nxt, out, (layer == 2) ? 0.25f : 1.0f);
            float* tmp = cur; cur = nxt; nxt = tmp;
        }
    }
}

// Round 9
// 550.045 us; speedup vs baseline: 2.1454x; 1.1494x over previous
//
#include <hip/hip_runtime.h>

#define N_USERS 200000
#define N_ITEMS 100000
#define N_NODES 300000
#define EMB     64
#define N_EDGES 5000000

typedef float f32x4 __attribute__((ext_vector_type(4)));
typedef _Float16 f16;
typedef f16 f16x4 __attribute__((ext_vector_type(4)));     // 8 B gather granule

// 8 B staged record: rc = (rowLow10 << 19) | col  (col < 2^19)
struct alignas(8) SRec { unsigned int rc; float val; };

#define BSHIFT 10
#define BROWS  (1 << BSHIFT)                               // 1024
#define NBUCK  ((N_NODES + BROWS - 1) >> BSHIFT)           // 293
#define CAP    20000                                       // mean 17065, sigma~130 (+22s)
#define BIN_CHUNK 16384                                    // edges per bin block (2-pass)
#define COLMASK 0x7FFFFu
#define INIT_BLOCKS 2048                                   // grid-strided init part

// ---------------------------------------------------------------------------
// Fused init + bin (R8 structure: batched pass-A loads, rows reused in regs).
// ---------------------------------------------------------------------------
__global__ __launch_bounds__(256) void fused_init_bin_kernel(
    const float* __restrict__ user, const float* __restrict__ item,
    f16* __restrict__ x0,
    const int4* __restrict__ row4, const int4* __restrict__ col4,
    const float4* __restrict__ val4,
    int* __restrict__ bcursor, SRec* __restrict__ stage, int bin_blocks)
{
    int t = threadIdx.x;
    if ((int)blockIdx.x < bin_blocks) {
        __shared__ int hist[NBUCK];
        __shared__ int base_[NBUCK];
        const int Q = N_EDGES / 4;                    // int4 count (N_EDGES%4==0)
        long q0 = (long)blockIdx.x * (BIN_CHUNK / 4); // 4096 int4 / block

        for (int k = t; k < NBUCK; k += 256) hist[k] = 0;
        __syncthreads();

        // ---- pass A: batch row loads, then count 16K edges ----
        int4 ra[16];
        const bool full = (q0 + (BIN_CHUNK / 4) <= Q);
        if (full) {
            #pragma unroll
            for (int k = 0; k < 16; ++k)
                ra[k] = row4[q0 + k * 256 + t];
            #pragma unroll
            for (int k = 0; k < 16; ++k) {
                atomicAdd(&hist[ra[k].x >> BSHIFT], 1);
                atomicAdd(&hist[ra[k].y >> BSHIFT], 1);
                atomicAdd(&hist[ra[k].z >> BSHIFT], 1);
                atomicAdd(&hist[ra[k].w >> BSHIFT], 1);
            }
        } else {
            #pragma unroll
            for (int k = 0; k < 16; ++k) {
                long q = q0 + k * 256 + t;
                if (q < Q) {
                    ra[k] = row4[q];
                    atomicAdd(&hist[ra[k].x >> BSHIFT], 1);
                    atomicAdd(&hist[ra[k].y >> BSHIFT], 1);
                    atomicAdd(&hist[ra[k].z >> BSHIFT], 1);
                    atomicAdd(&hist[ra[k].w >> BSHIFT], 1);
                }
            }
        }
        __syncthreads();
        // one claim per bucket for the whole 16K chunk -> dense runs
        for (int k = t; k < NBUCK; k += 256) {
            int h = hist[k];
            base_[k] = h ? atomicAdd(&bcursor[k], h) : 0;
            hist[k] = 0;                               // reuse as local cursor
        }
        __syncthreads();
        // ---- pass B: col/val batched x4, rows from registers ----
        #pragma unroll
        for (int g = 0; g < 4; ++g) {
            int4 c4[4]; float4 v4[4];
            #pragma unroll
            for (int j = 0; j < 4; ++j) {
                long q = q0 + (g * 4 + j) * 256 + t;
                if (q < Q) { c4[j] = col4[q]; v4[j] = val4[q]; }
            }
            #pragma unroll
            for (int j = 0; j < 4; ++j) {
                long q = q0 + (g * 4 + j) * 256 + t;
                if (q < Q) {
                    int4 r = ra[g * 4 + j];
                    int   rr[4] = {r.x, r.y, r.z, r.w};
                    int   cc[4] = {c4[j].x, c4[j].y, c4[j].z, c4[j].w};
                    float vv[4] = {v4[j].x, v4[j].y, v4[j].z, v4[j].w};
                    #pragma unroll
                    for (int m = 0; m < 4; ++m) {
                        int b   = rr[m] >> BSHIFT;
                        int pos = base_[b] + atomicAdd(&hist[b], 1);
                        SRec s;
                        s.rc  = ((unsigned)(rr[m] & (BROWS - 1)) << 19)
                              | (unsigned)cc[m];
                        s.val = vv[m];
                        stage[(size_t)b * CAP + pos] = s;
                    }
                }
            }
        }
    } else {
        const int nu4 = N_USERS * EMB / 4;
        const int nt4 = N_NODES * EMB / 4;
        int i0 = ((int)blockIdx.x - bin_blocks) * 256 + t;
        const int stride = INIT_BLOCKS * 256;
        for (int i = i0; i < nt4; i += stride) {
            float4 vv = (i < nu4) ? reinterpret_cast<const float4*>(user)[i]
                                  : reinterpret_cast<const float4*>(item)[i - nu4];
            f16x4 hx = {(f16)vv.x, (f16)vv.y, (f16)vv.z, (f16)vv.w};
            reinterpret_cast<f16x4*>(x0)[i] = hx;
        }
    }
}

// ---------------------------------------------------------------------------
// Per-bucket: count -> scan -> scatter INTO LDS -> dense stream-out.
// R8 PMC: WRITE_SIZE 320 MB vs 31 MB payload (10x sector amplification from
// scattered 4 B/2 B global writes; 37 co-resident windows/XCD thrash the
// 4 MB L2 so lines evict mid-fill). Fix: row-sort entirely in LDS
// (lcol 80 KB + lval 40 KB, ~126 KiB total), then write pcol/pval as
// coalesced sequential streams = payload-only line-dense writes.
// ---------------------------------------------------------------------------
__global__ __launch_bounds__(1024) void bucket_scan_scatter_kernel(
    const SRec* __restrict__ stage, const int* __restrict__ bsize,
    int* __restrict__ start, int* __restrict__ pcol, f16* __restrict__ pval)
{
    __shared__ int sizes[NBUCK];
    __shared__ int cur[BROWS];
    __shared__ int sc[1024];
    __shared__ int lcol[CAP];
    __shared__ f16 lval[CAP];
    __shared__ int sbase;

    int b    = blockIdx.x;
    int t    = threadIdx.x;
    int row0 = b << BSHIFT;
    int rows = N_NODES - row0; if (rows > BROWS) rows = BROWS;

    if (t < NBUCK) sizes[t] = bsize[t];
    cur[t] = 0;                         // per-row count first
    __syncthreads();
    if (t == 0) {                       // bucket base: serial prefix over LDS
        int s = 0;
        for (int k = 0; k < b; ++k) s += sizes[k];
        sbase = s;
    }
    __syncthreads();
    const int  base = sbase;
    const int  size = sizes[b];
    const SRec* seg = stage + (size_t)b * CAP;

    // pass A: per-row counts
    for (int e = t; e < size; e += 1024)
        atomicAdd(&cur[seg[e].rc >> 19], 1);
    __syncthreads();

    // exclusive scan over 1024 counts (local, Hillis-Steele)
    int a = cur[t];
    sc[t] = a;
    __syncthreads();
    for (int ofs = 1; ofs < 1024; ofs <<= 1) {
        int v = (t >= ofs) ? sc[t - ofs] : 0;
        __syncthreads();
        sc[t] += v;
        __syncthreads();
    }
    int excl = sc[t] - a;
    cur[t] = excl;                      // LOCAL cursor (no base)
    if (t < rows) start[row0 + t] = base + excl;
    if (b == NBUCK - 1 && t == 0) start[N_NODES] = N_EDGES;
    __syncthreads();

    // pass B: scatter into LDS (seg L2-warm from pass A)
    for (int e = t; e < size; e += 1024) {
        SRec srec = seg[e];
        int idx = atomicAdd(&cur[srec.rc >> 19], 1);
        lcol[idx] = (int)(srec.rc & COLMASK);
        lval[idx] = (f16)srec.val;
    }
    __syncthreads();

    // stream out: dense, coalesced, payload-only
    for (int i = t; i < size; i += 1024) pcol[base + i] = lcol[i];
    for (int i = t; i < size; i += 1024) pval[base + i] = lval[i];
}

// ---------------------------------------------------------------------------
// CSR SpMM over fp16 tables. mode 0: write y only (layers 0,1). mode 1
// (layer 2): epilogue out = 0.25*(x0 + x1 + x2 + acc), write-only out.
// Established: miss-path-byte-bound at ~3.87 TB/s; dur tracks bytes exactly.
// ---------------------------------------------------------------------------
__global__ __launch_bounds__(256, 4) void spmm_csr_kernel(
    const f16* __restrict__ x, const int* __restrict__ pcol,
    const f16* __restrict__ pval, const int* __restrict__ start,
    f16* __restrict__ y,
    const f16* __restrict__ xa, const f16* __restrict__ xb,
    float* __restrict__ out, int mode)
{
    int g = blockIdx.x * (256 / 16) + (threadIdx.x >> 4);
    if (g >= N_NODES) return;
    const int lane16 = threadIdx.x & 15;
    const int d      = lane16 * 4;
    const int gbase  = threadIdx.x & 48;

    int beg = start[g];
    int end = start[g + 1];
    float4 acc = {0.f, 0.f, 0.f, 0.f};

    for (int jb = beg; jb < end; jb += 16) {
        int   mycol = 0; float myval = 0.f;
        if (jb + lane16 < end) {
            mycol = pcol[jb + lane16];
            myval = (float)pval[jb + lane16];
        }

        int   cols[16];
        float vals[16];
        #pragma unroll
        for (int k = 0; k < 16; ++k) {
            cols[k] = __shfl(mycol, gbase + k, 64);
            vals[k] = __shfl(myval, gbase + k, 64);
        }

        f16x4 xv[16];
        #pragma unroll
        for (int k = 0; k < 16; ++k) {
            xv[k] = *reinterpret_cast<const f16x4*>(
                x + (size_t)cols[k] * EMB + d);
        }

        #pragma unroll
        for (int k = 0; k < 16; ++k) {
            acc.x += vals[k] * (float)xv[k].x;
            acc.y += vals[k] * (float)xv[k].y;
            acc.z += vals[k] * (float)xv[k].z;
            acc.w += vals[k] * (float)xv[k].w;
        }
    }

    const size_t rofs = (size_t)g * EMB + d;
    if (mode == 0) {
        f16x4 hy = {(f16)acc.x, (f16)acc.y, (f16)acc.z, (f16)acc.w};
        *reinterpret_cast<f16x4*>(y + rofs) = hy;
    } else {
        f16x4 v0 = *reinterpret_cast<const f16x4*>(xa + rofs);
        f16x4 v1 = *reinterpret_cast<const f16x4*>(xb + rofs);
        f16x4 v2 = *reinterpret_cast<const f16x4*>(x  + rofs);
        f32x4 o;
        o.x = 0.25f * ((float)v0.x + (float)v1.x + (float)v2.x + acc.x);
        o.y = 0.25f * ((float)v0.y + (float)v1.y + (float)v2.y + acc.y);
        o.z = 0.25f * ((float)v0.z + (float)v1.z + (float)v2.z + acc.z);
        o.w = 0.25f * ((float)v0.w + (float)v1.w + (float)v2.w + acc.w);
        __builtin_nontemporal_store(o, reinterpret_cast<f32x4*>(out + rofs));
    }
}

// ---------------------------------------------------------------------------
// Fallback path (ws too small for CSR): unchanged fp32 atomic path.
// ---------------------------------------------------------------------------
__global__ __launch_bounds__(256) void init_kernel(
    const float* __restrict__ user, const float* __restrict__ item,
    float* __restrict__ x, float* __restrict__ out)
{
    const int nu4 = N_USERS * EMB / 4;
    const int nt4 = N_NODES * EMB / 4;
    int i = blockIdx.x * blockDim.x + threadIdx.x;
    if (i >= nt4) return;
    float4 v = (i < nu4) ? reinterpret_cast<const float4*>(user)[i]
                         : reinterpret_cast<const float4*>(item)[i - nu4];
    reinterpret_cast<float4*>(x)[i]   = v;
    reinterpret_cast<float4*>(out)[i] = v;
}

__global__ __launch_bounds__(256) void spmm_atomic_kernel(
    const float* __restrict__ x, const float* __restrict__ val,
    const int* __restrict__ row, const int* __restrict__ col,
    float* __restrict__ y)
{
    int t = blockIdx.x * blockDim.x + threadIdx.x;
    int e = t >> 4;
    if (e >= N_EDGES) return;
    int d = (t & 15) * 4;
    int   r = row[e];
    int   c = col[e];
    float v = val[e];
    float4 xv = *reinterpret_cast<const float4*>(x + c * EMB + d);
    float* yp = y + r * EMB + d;
    unsafeAtomicAdd(yp + 0, v * xv.x);
    unsafeAtomicAdd(yp + 1, v * xv.y);
    unsafeAtomicAdd(yp + 2, v * xv.z);
    unsafeAtomicAdd(yp + 3, v * xv.w);
}

__global__ __launch_bounds__(256) void addscale_kernel(
    const float* __restrict__ xl, float* __restrict__ out, float scale)
{
    const int nt4 = N_NODES * EMB / 4;
    int i = blockIdx.x * blockDim.x + threadIdx.x;
    if (i >= nt4) return;
    float4 a = reinterpret_cast<float4*>(out)[i];
    float4 b = reinterpret_cast<const float4*>(xl)[i];
    a.x = (a.x + b.x) * scale;
    a.y = (a.y + b.y) * scale;
    a.z = (a.z + b.z) * scale;
    a.w = (a.w + b.w) * scale;
    reinterpret_cast<float4*>(out)[i] = a;
}

extern "C" void kernel_launch(void* const* d_in, const int* in_sizes, int n_in,
                              void* d_out, int out_size, void* d_ws, size_t ws_size,
                              hipStream_t stream) {
    const float* emb_user = (const float*)d_in[0];
    const float* emb_item = (const float*)d_in[1];
    const float* edge_val = (const float*)d_in[2];
    const int*   edge_row = (const int*)d_in[3];
    const int*   edge_col = (const int*)d_in[4];
    float* out = (float*)d_out;

    const size_t node_elems = (size_t)N_NODES * EMB;        // 19.2M elems
    char* ws = (char*)d_ws;

    // workspace layout:
    //  region A (76.8 MB): x0 fp16 [0,38.4) | x2 fp16 [38.4,76.8)
    //  region B (76.8 MB): stage 47 MB during build; x1 fp16 [0,38.4) after
    //  packed SoA: cols 20 MB + vals 10 MB
    const size_t off_bufA    = 0;
    const size_t off_bufB    = off_bufA + node_elems * sizeof(float);      // 76.8 MB
    const size_t off_pcol    = off_bufB + node_elems * sizeof(float);      // 153.6 MB
    const size_t off_pval    = off_pcol + (size_t)N_EDGES * sizeof(int);   // 173.6 MB
    const size_t off_start   = off_pval + (size_t)N_EDGES * sizeof(f16);   // 183.6 MB
    const size_t off_bcursor = off_start + (N_NODES + 4) * sizeof(int);
    const size_t needed      = off_bcursor + (NBUCK + 4) * sizeof(int);    // ~185 MB

    const int nt4       = N_NODES * EMB / 4;
    const int el_blocks = (nt4 + 255) / 256;
    const int e_blocks  = (N_EDGES + 255) / 256;

    static_assert((size_t)NBUCK * CAP * sizeof(SRec) <= (size_t)N_NODES * EMB * sizeof(float),
                  "stage must fit in bufB region");

    if (ws_size >= needed) {
        // ---- CSR path (fp16 tables, SoA packed, deferred combine) ----
        f16*  x0buf   = (f16*) (ws + off_bufA);
        f16*  x2buf   = (f16*) (ws + off_bufA) + node_elems;   // +38.4 MB
        f16*  x1buf   = (f16*) (ws + off_bufB);
        int*  pcol    = (int*) (ws + off_pcol);
        f16*  pval    = (f16*) (ws + off_pval);
        int*  start   = (int*) (ws + off_start);
        int*  bcursor = (int*) (ws + off_bcursor);
        SRec* stage   = (SRec*)(ws + off_bufB);   // dead after scatter; x1 reuses

        hipMemsetAsync(bcursor, 0, (NBUCK + 4) * sizeof(int), stream);

        const int bin_blocks = (N_EDGES + BIN_CHUNK - 1) / BIN_CHUNK;      // 306
        fused_init_bin_kernel<<<bin_blocks + INIT_BLOCKS, 256, 0, stream>>>(
            emb_user, emb_item, x0buf,
            (const int4*)edge_row, (const int4*)edge_col, (const float4*)edge_val,
            bcursor, stage, bin_blocks);

        bucket_scan_scatter_kernel<<<NBUCK, 1024, 0, stream>>>(
            stage, bcursor, start, pcol, pval);

        const int row_blocks = (N_NODES + 15) / 16;
        // L0: x0 -> x1   (x1 overwrites stage: stage is dead after scatter)
        spmm_csr_kernel<<<row_blocks, 256, 0, stream>>>(
            x0buf, pcol, pval, start, x1buf, nullptr, nullptr, nullptr, 0);
        // L1: x1 -> x2
        spmm_csr_kernel<<<row_blocks, 256, 0, stream>>>(
            x1buf, pcol, pval, start, x2buf, nullptr, nullptr, nullptr, 0);
        // L2: x2 -> epilogue: out = 0.25*(x0+x1+x2+acc), write-only out
        spmm_csr_kernel<<<row_blocks, 256, 0, stream>>>(
            x2buf, pcol, pval, start, nullptr, x0buf, x1buf, out, 1);
    } else {
        // ---- fallback: fp32 atomic path (needs only 153.6 MB) ----
        float* fbufA = (float*)(ws + off_bufA);
        float* fbufB = (float*)(ws + off_bufB);
        init_kernel<<<el_blocks, 256, 0, stream>>>(emb_user, emb_item, fbufA, out);
        const int ew_blocks = (N_EDGES * 16 + 255) / 256;
        float* cur = fbufA;
        float* nxt = fbufB;
        for (int layer = 0; layer < 3; ++layer) {
            hipMemsetAsync(nxt, 0, node_elems * sizeof(float), stream);
            spmm_atomic_kernel<<<ew_blocks, 256, 0, stream>>>(
                cur, edge_val, edge_row, edge_col, nxt);
            addscale_kernel<<<el_blocks, 256, 0, stream>>>(
                nxt, out, (layer == 2) ? 0.25f : 1.0f);
            float* tmp = cur; cur = nxt; nxt = tmp;
        }
    }
}